// Round 5
// baseline (550.724 us; speedup 1.0000x reference)
//
#include <hip/hip_runtime.h>

#define N_NODES 50000
#define N_EDGES 800000
#define D 64
#define NB 196            // buckets / owner blocks; 196*256 = 50176 >= 50000
#define BSZ 256           // nodes per bucket (pow2: bucket = id >> 8)
#define NSLICE 196        // edge slices; 196*4096 = 802816 >= 800000
#define E4 (N_EDGES / 4)  // 200000 int4 groups (800000 % 4 == 0)
#define SCAN_N (NB * NSLICE)  // 38416
#define SCAN_C 38         // 1024*38 = 38912 >= 38416

// ---------------------------------------------------------------------------
// K1: per-slice bucket histograms (receiver and sender), no global atomics.
// Slice = 4096 edges (1024 threads x int4). cnt layout: [bucket][slice].
// ---------------------------------------------------------------------------
__global__ __launch_bounds__(1024) void count_kernel(
        const int* __restrict__ s, const int* __restrict__ r,
        int* __restrict__ rcnt, int* __restrict__ scnt) {
    __shared__ int rh[NB], sh[NB];
    const int tid = threadIdx.x, sl = blockIdx.x;
    for (int i = tid; i < NB; i += 1024) { rh[i] = 0; sh[i] = 0; }
    __syncthreads();

    int e4 = sl * 1024 + tid;
    if (e4 < E4) {
        int4 rv = ((const int4*)r)[e4];
        int4 sv = ((const int4*)s)[e4];
        atomicAdd(&rh[rv.x >> 8], 1); atomicAdd(&rh[rv.y >> 8], 1);
        atomicAdd(&rh[rv.z >> 8], 1); atomicAdd(&rh[rv.w >> 8], 1);
        atomicAdd(&sh[sv.x >> 8], 1); atomicAdd(&sh[sv.y >> 8], 1);
        atomicAdd(&sh[sv.z >> 8], 1); atomicAdd(&sh[sv.w >> 8], 1);
    }
    __syncthreads();
    for (int i = tid; i < NB; i += 1024) {
        rcnt[i * NSLICE + sl] = rh[i];
        scnt[i * NSLICE + sl] = sh[i];
    }
}

// ---------------------------------------------------------------------------
// K2: in-place exclusive scan of both count arrays (single block).
// ---------------------------------------------------------------------------
__global__ __launch_bounds__(1024) void scan_kernel(int* __restrict__ a,
                                                    int* __restrict__ b) {
    __shared__ int sc[1024];
    const int tid = threadIdx.x;
    for (int pass = 0; pass < 2; ++pass) {
        int* arr = pass ? b : a;
        const int base = tid * SCAN_C;
        int sum = 0;
        for (int j = 0; j < SCAN_C; ++j) {
            int idx = base + j;
            if (idx < SCAN_N) sum += arr[idx];
        }
        sc[tid] = sum;
        __syncthreads();
        for (int o = 1; o < 1024; o <<= 1) {
            int u = (tid >= o) ? sc[tid - o] : 0;
            __syncthreads();
            sc[tid] += u;
            __syncthreads();
        }
        int run = sc[tid] - sum;  // exclusive prefix of this thread's chunk
        for (int j = 0; j < SCAN_C; ++j) {
            int idx = base + j;
            if (idx < SCAN_N) { int v = arr[idx]; arr[idx] = run; run += v; }
        }
        __syncthreads();
    }
}

// ---------------------------------------------------------------------------
// K3: radix partition. Writes receiver-bucketed packed pairs (rl<<16 | s)
// and sender-bucketed local ids (u8). LDS cursor atomics only.
// ---------------------------------------------------------------------------
__global__ __launch_bounds__(1024) void part_kernel(
        const int* __restrict__ s, const int* __restrict__ r,
        const int* __restrict__ rcnt, const int* __restrict__ scnt,
        unsigned* __restrict__ pr, unsigned char* __restrict__ ps8) {
    __shared__ int rcur[NB], scur[NB];
    const int tid = threadIdx.x, sl = blockIdx.x;
    for (int i = tid; i < NB; i += 1024) {
        rcur[i] = rcnt[i * NSLICE + sl];
        scur[i] = scnt[i * NSLICE + sl];
    }
    __syncthreads();

    int e4 = sl * 1024 + tid;
    if (e4 < E4) {
        int4 rv = ((const int4*)r)[e4];
        int4 sv = ((const int4*)s)[e4];
        int ri[4] = {rv.x, rv.y, rv.z, rv.w};
        int si[4] = {sv.x, sv.y, sv.z, sv.w};
        #pragma unroll
        for (int k = 0; k < 4; ++k) {
            int pos = atomicAdd(&rcur[ri[k] >> 8], 1);
            pr[pos] = ((unsigned)(ri[k] & 255) << 16) | (unsigned)si[k];
            int pos2 = atomicAdd(&scur[si[k] >> 8], 1);
            ps8[pos2] = (unsigned char)(si[k] & 255);
        }
    }
}

// ---------------------------------------------------------------------------
// K4: node-level sender degree from the u8 partition -> sscale.
// ---------------------------------------------------------------------------
__global__ __launch_bounds__(256) void sscale_kernel(
        const int* __restrict__ scnt, const unsigned char* __restrict__ ps8,
        float* __restrict__ sscale) {
    __shared__ int hist[BSZ];
    const int b = blockIdx.x, tid = threadIdx.x;
    hist[tid] = 0;
    __syncthreads();
    int sb = scnt[b * NSLICE];
    int se = (b == NB - 1) ? N_EDGES : scnt[(b + 1) * NSLICE];
    for (int i = sb + tid; i < se; i += 256) atomicAdd(&hist[ps8[i]], 1);
    __syncthreads();
    int n = b * BSZ + tid;
    if (n < N_NODES) sscale[n] = rsqrtf((float)(hist[tid] + 1));  // +1 self edge
}

// ---------------------------------------------------------------------------
// K5: h = (x @ W^T + b) * sscale[n]. Wave per node, lane = out channel.
// ---------------------------------------------------------------------------
__global__ __launch_bounds__(256) void linear_kernel(
        const float* __restrict__ x, const float* __restrict__ w,
        const float* __restrict__ bias, const float* __restrict__ sscale,
        float* __restrict__ h) {
    const int lane = threadIdx.x & 63;
    const int wid = blockIdx.x * 4 + (threadIdx.x >> 6);
    const int nwaves = gridDim.x * 4;

    float4 wreg[16];
    #pragma unroll
    for (int i = 0; i < 16; ++i) wreg[i] = ((const float4*)w)[lane * 16 + i];
    const float bo = bias[lane];

    for (int n = wid; n < N_NODES; n += nwaves) {
        const float4* xr = (const float4*)(x + n * D);
        float a0 = 0.f, a1 = 0.f, a2 = 0.f, a3 = 0.f;
        #pragma unroll
        for (int i = 0; i < 16; i += 4) {
            float4 x0 = xr[i], x1 = xr[i + 1], x2 = xr[i + 2], x3 = xr[i + 3];
            a0 += x0.x * wreg[i].x + x0.y * wreg[i].y + x0.z * wreg[i].z + x0.w * wreg[i].w;
            a1 += x1.x * wreg[i+1].x + x1.y * wreg[i+1].y + x1.z * wreg[i+1].z + x1.w * wreg[i+1].w;
            a2 += x2.x * wreg[i+2].x + x2.y * wreg[i+2].y + x2.z * wreg[i+2].z + x2.w * wreg[i+2].w;
            a3 += x3.x * wreg[i+3].x + x3.y * wreg[i+3].y + x3.z * wreg[i+3].z + x3.w * wreg[i+3].w;
        }
        h[n * D + lane] = (bo + (a0 + a1) + (a2 + a3)) * sscale[n];
    }
}

// ---------------------------------------------------------------------------
// K6: bucketed scatter-accumulate. Block b owns nodes [b*256,(b+1)*256) in a
// 64KB LDS fp32 tile; reads only its own bucket's pairs (contiguous); per
// edge: coalesced 256B h-row gather -> LDS float atomic. rdeg counted in
// LDS. Finalize: self-term + rsqrt + leaky-relu, coalesced store.
// ---------------------------------------------------------------------------
__global__ __launch_bounds__(1024) void scatter_kernel(
        const unsigned* __restrict__ pr, const int* __restrict__ rcnt,
        const float* __restrict__ h, float* __restrict__ out) {
    __shared__ float accf[BSZ * D];   // 64 KB
    __shared__ int rdl[BSZ];
    const int tid = threadIdx.x, lane = tid & 63, wv = tid >> 6;
    const int b = blockIdx.x;

    for (int i = tid; i < BSZ * D; i += 1024) accf[i] = 0.0f;
    for (int i = tid; i < BSZ; i += 1024) rdl[i] = 0;
    __syncthreads();

    const int rb = rcnt[b * NSLICE];
    const int re = (b == NB - 1) ? N_EDGES : rcnt[(b + 1) * NSLICE];
    const int m = re - rb;
    const int chunk = (m + 15) >> 4;
    int i = rb + wv * chunk;
    const int wend = min(i + chunk, re);

    for (; i + 8 <= wend; i += 8) {
        unsigned pw[8];
        #pragma unroll
        for (int k = 0; k < 8; ++k) pw[k] = pr[i + k];
        float vv[8];
        #pragma unroll
        for (int k = 0; k < 8; ++k) vv[k] = h[(pw[k] & 0xffffu) * D + lane];
        #pragma unroll
        for (int k = 0; k < 8; ++k) {
            int rl = (int)(pw[k] >> 16);
            atomicAdd(&accf[rl * D + lane], vv[k]);
            if (lane == 0) atomicAdd(&rdl[rl], 1);
        }
    }
    for (; i < wend; ++i) {
        unsigned pw = pr[i];
        float v = h[(pw & 0xffffu) * D + lane];
        int rl = (int)(pw >> 16);
        atomicAdd(&accf[rl * D + lane], v);
        if (lane == 0) atomicAdd(&rdl[rl], 1);
    }
    __syncthreads();

    for (int j = tid; j < BSZ * D; j += 1024) {
        int nl = j >> 6;
        int n = b * BSZ + nl;
        if (n < N_NODES) {
            int d = j & 63;
            float vv = (accf[j] + h[n * D + d]) * rsqrtf((float)(rdl[nl] + 1));
            out[n * D + d] = vv > 0.0f ? vv : 0.01f * vv;
        }
    }
}

// ---------------------------------------------------------------------------
extern "C" void kernel_launch(void* const* d_in, const int* in_sizes, int n_in,
                              void* d_out, int out_size, void* d_ws, size_t ws_size,
                              hipStream_t stream) {
    const float* x       = (const float*)d_in[0];
    const int*   senders = (const int*)d_in[1];
    const int*   recvs   = (const int*)d_in[2];
    const float* weight  = (const float*)d_in[3];
    const float* bias    = (const float*)d_in[4];
    float* out = (float*)d_out;

    // workspace layout (256B-aligned chunks)
    char* p = (char*)d_ws;
    auto take = [&](size_t bytes) { char* q = p; p += (bytes + 255) & ~(size_t)255; return q; };
    float*         h      = (float*)take((size_t)N_NODES * D * 4);   // 12.8 MB
    float*         sscale = (float*)take((size_t)N_NODES * 4);       // 200 KB
    unsigned*      pr     = (unsigned*)take((size_t)N_EDGES * 4);    // 3.2 MB
    unsigned char* ps8    = (unsigned char*)take((size_t)N_EDGES);   // 0.8 MB
    int*           rcnt   = (int*)take((size_t)SCAN_N * 4);          // 150 KB
    int*           scnt   = (int*)take((size_t)SCAN_N * 4);          // 150 KB

    hipLaunchKernelGGL(count_kernel, dim3(NSLICE), dim3(1024), 0, stream,
                       senders, recvs, rcnt, scnt);
    hipLaunchKernelGGL(scan_kernel, dim3(1), dim3(1024), 0, stream, rcnt, scnt);
    hipLaunchKernelGGL(part_kernel, dim3(NSLICE), dim3(1024), 0, stream,
                       senders, recvs, rcnt, scnt, pr, ps8);
    hipLaunchKernelGGL(sscale_kernel, dim3(NB), dim3(BSZ), 0, stream,
                       scnt, ps8, sscale);
    hipLaunchKernelGGL(linear_kernel, dim3(1024), dim3(256), 0, stream,
                       x, weight, bias, sscale, h);
    hipLaunchKernelGGL(scatter_kernel, dim3(NB), dim3(1024), 0, stream,
                       pr, rcnt, h, out);
}

// Round 6
// 234.090 us; speedup vs baseline: 2.3526x; 2.3526x over previous
//
#include <hip/hip_runtime.h>

#define N_NODES 50000
#define N_EDGES 800000
#define D 64
#define NB 196            // buckets; 196*256 = 50176 >= 50000 (bucket = id >> 8)
#define BSZ 256           // nodes per bucket
#define NSLICE 196        // edge slices; 196*4096 = 802816 >= 800000
#define E4 (N_EDGES / 4)  // 200000 int4 groups
#define SCAN_N (NB * NSLICE)  // 38416
#define SCAN_C 38         // 1024*38 = 38912 >= 38416

// ---------------------------------------------------------------------------
// K1: per-slice bucket histograms (receiver and sender). No global atomics.
// ---------------------------------------------------------------------------
__global__ __launch_bounds__(1024) void count_kernel(
        const int* __restrict__ s, const int* __restrict__ r,
        int* __restrict__ rcnt, int* __restrict__ scnt) {
    __shared__ int rh[NB], sh[NB];
    const int tid = threadIdx.x, sl = blockIdx.x;
    for (int i = tid; i < NB; i += 1024) { rh[i] = 0; sh[i] = 0; }
    __syncthreads();

    int e4 = sl * 1024 + tid;
    if (e4 < E4) {
        int4 rv = ((const int4*)r)[e4];
        int4 sv = ((const int4*)s)[e4];
        atomicAdd(&rh[rv.x >> 8], 1); atomicAdd(&rh[rv.y >> 8], 1);
        atomicAdd(&rh[rv.z >> 8], 1); atomicAdd(&rh[rv.w >> 8], 1);
        atomicAdd(&sh[sv.x >> 8], 1); atomicAdd(&sh[sv.y >> 8], 1);
        atomicAdd(&sh[sv.z >> 8], 1); atomicAdd(&sh[sv.w >> 8], 1);
    }
    __syncthreads();
    for (int i = tid; i < NB; i += 1024) {
        rcnt[i * NSLICE + sl] = rh[i];
        scnt[i * NSLICE + sl] = sh[i];
    }
}

// ---------------------------------------------------------------------------
// K2: in-place exclusive scan of both count arrays (single block).
// ---------------------------------------------------------------------------
__global__ __launch_bounds__(1024) void scan_kernel(int* __restrict__ a,
                                                    int* __restrict__ b) {
    __shared__ int sc[1024];
    const int tid = threadIdx.x;
    for (int pass = 0; pass < 2; ++pass) {
        int* arr = pass ? b : a;
        const int base = tid * SCAN_C;
        int sum = 0;
        for (int j = 0; j < SCAN_C; ++j) {
            int idx = base + j;
            if (idx < SCAN_N) sum += arr[idx];
        }
        sc[tid] = sum;
        __syncthreads();
        for (int o = 1; o < 1024; o <<= 1) {
            int u = (tid >= o) ? sc[tid - o] : 0;
            __syncthreads();
            sc[tid] += u;
            __syncthreads();
        }
        int run = sc[tid] - sum;
        for (int j = 0; j < SCAN_C; ++j) {
            int idx = base + j;
            if (idx < SCAN_N) { int v = arr[idx]; arr[idx] = run; run += v; }
        }
        __syncthreads();
    }
}

// ---------------------------------------------------------------------------
// K3: radix partition. Receiver-bucketed packed pairs (rl<<16 | s) and
// sender-bucketed local ids (u8). LDS cursor atomics only.
// ---------------------------------------------------------------------------
__global__ __launch_bounds__(1024) void part_kernel(
        const int* __restrict__ s, const int* __restrict__ r,
        const int* __restrict__ rcnt, const int* __restrict__ scnt,
        unsigned* __restrict__ pr, unsigned char* __restrict__ ps8) {
    __shared__ int rcur[NB], scur[NB];
    const int tid = threadIdx.x, sl = blockIdx.x;
    for (int i = tid; i < NB; i += 1024) {
        rcur[i] = rcnt[i * NSLICE + sl];
        scur[i] = scnt[i * NSLICE + sl];
    }
    __syncthreads();

    int e4 = sl * 1024 + tid;
    if (e4 < E4) {
        int4 rv = ((const int4*)r)[e4];
        int4 sv = ((const int4*)s)[e4];
        int ri[4] = {rv.x, rv.y, rv.z, rv.w};
        int si[4] = {sv.x, sv.y, sv.z, sv.w};
        #pragma unroll
        for (int k = 0; k < 4; ++k) {
            int pos = atomicAdd(&rcur[ri[k] >> 8], 1);
            pr[pos] = ((unsigned)(ri[k] & 255) << 16) | (unsigned)si[k];
            int pos2 = atomicAdd(&scur[si[k] >> 8], 1);
            ps8[pos2] = (unsigned char)(si[k] & 255);
        }
    }
}

// ---------------------------------------------------------------------------
// K4: node-level sender degree from the u8 partition -> sscale.
// ---------------------------------------------------------------------------
__global__ __launch_bounds__(256) void sscale_kernel(
        const int* __restrict__ scnt, const unsigned char* __restrict__ ps8,
        float* __restrict__ sscale) {
    __shared__ int hist[BSZ];
    const int b = blockIdx.x, tid = threadIdx.x;
    hist[tid] = 0;
    __syncthreads();
    int sb = scnt[b * NSLICE];
    int se = (b == NB - 1) ? N_EDGES : scnt[(b + 1) * NSLICE];
    for (int i = sb + tid; i < se; i += 256) atomicAdd(&hist[ps8[i]], 1);
    __syncthreads();
    int n = b * BSZ + tid;
    if (n < N_NODES) sscale[n] = rsqrtf((float)(hist[tid] + 1));  // +1 self edge
}

// ---------------------------------------------------------------------------
// K5: per-bucket CSR finalize: node-level hist + LDS scan -> rowoff, then
// cursor-scatter senders (u16) into per-node-sorted csr16. 196 blocks,
// each reads its ~4k contiguous pairs twice. LDS atomics only.
// ---------------------------------------------------------------------------
__global__ __launch_bounds__(256) void csr_kernel(
        const unsigned* __restrict__ pr, const int* __restrict__ rcnt,
        int* __restrict__ rowoff, ushort* __restrict__ csr16) {
    __shared__ int hist[BSZ];
    __shared__ int cur[BSZ];
    const int b = blockIdx.x, tid = threadIdx.x;
    const int rb = rcnt[b * NSLICE];
    const int re = (b == NB - 1) ? N_EDGES : rcnt[(b + 1) * NSLICE];

    hist[tid] = 0;
    __syncthreads();
    for (int i = rb + tid; i < re; i += 256)
        atomicAdd(&hist[pr[i] >> 16], 1);
    __syncthreads();

    // Hillis-Steele inclusive scan over 256 entries
    int v = hist[tid];
    int sc = v;
    __syncthreads();
    hist[tid] = sc;
    __syncthreads();
    for (int o = 1; o < 256; o <<= 1) {
        int u = (tid >= o) ? hist[tid - o] : 0;
        __syncthreads();
        hist[tid] += u;
        __syncthreads();
    }
    int excl = hist[tid] - v;  // exclusive local prefix
    int n = b * BSZ + tid;
    if (n < N_NODES) rowoff[n] = rb + excl;
    cur[tid] = rb + excl;
    if (b == NB - 1 && tid == 0) rowoff[N_NODES] = N_EDGES;
    __syncthreads();

    for (int i = rb + tid; i < re; i += 256) {
        unsigned pw = pr[i];
        int pos = atomicAdd(&cur[pw >> 16], 1);
        csr16[pos] = (ushort)(pw & 0xffffu);
    }
}

// ---------------------------------------------------------------------------
// K6: h = (x @ W^T + b) * sscale[n]. Wave per node, lane = out channel.
// ---------------------------------------------------------------------------
__global__ __launch_bounds__(256) void linear_kernel(
        const float* __restrict__ x, const float* __restrict__ w,
        const float* __restrict__ bias, const float* __restrict__ sscale,
        float* __restrict__ h) {
    const int lane = threadIdx.x & 63;
    const int wid = blockIdx.x * 4 + (threadIdx.x >> 6);
    const int nwaves = gridDim.x * 4;

    float4 wreg[16];
    #pragma unroll
    for (int i = 0; i < 16; ++i) wreg[i] = ((const float4*)w)[lane * 16 + i];
    const float bo = bias[lane];

    for (int n = wid; n < N_NODES; n += nwaves) {
        const float4* xr = (const float4*)(x + n * D);
        float a0 = 0.f, a1 = 0.f, a2 = 0.f, a3 = 0.f;
        #pragma unroll
        for (int i = 0; i < 16; i += 4) {
            float4 x0 = xr[i], x1 = xr[i + 1], x2 = xr[i + 2], x3 = xr[i + 3];
            a0 += x0.x * wreg[i].x + x0.y * wreg[i].y + x0.z * wreg[i].z + x0.w * wreg[i].w;
            a1 += x1.x * wreg[i+1].x + x1.y * wreg[i+1].y + x1.z * wreg[i+1].z + x1.w * wreg[i+1].w;
            a2 += x2.x * wreg[i+2].x + x2.y * wreg[i+2].y + x2.z * wreg[i+2].z + x2.w * wreg[i+2].w;
            a3 += x3.x * wreg[i+3].x + x3.y * wreg[i+3].y + x3.z * wreg[i+3].z + x3.w * wreg[i+3].w;
        }
        h[n * D + lane] = (bo + (a0 + a1) + (a2 + a3)) * sscale[n];
    }
}

// ---------------------------------------------------------------------------
// K7: gather-accumulate per receiver + self-term + rsqrt + leaky-relu.
// Wave per node (12500 blocks -> full occupancy), 8-deep load batching.
// ---------------------------------------------------------------------------
__global__ __launch_bounds__(256) void gather_kernel(
        const float* __restrict__ h, const int* __restrict__ rowoff,
        const ushort* __restrict__ csr16, float* __restrict__ out) {
    const int lane = threadIdx.x & 63;
    const int n = blockIdx.x * 4 + (threadIdx.x >> 6);
    if (n >= N_NODES) return;

    float acc = h[n * D + lane];           // self-edge contribution
    const int base = rowoff[n];
    const int cnt = rowoff[n + 1] - base;

    for (int j0 = 0; j0 < cnt; j0 += 64) {
        int m = cnt - j0; if (m > 64) m = 64;
        int my = (lane < m) ? (int)csr16[base + j0 + lane] : 0;
        int t = 0;
        for (; t + 8 <= m; t += 8) {
            float a0 = h[__shfl(my, t + 0) * D + lane];
            float a1 = h[__shfl(my, t + 1) * D + lane];
            float a2 = h[__shfl(my, t + 2) * D + lane];
            float a3 = h[__shfl(my, t + 3) * D + lane];
            float a4 = h[__shfl(my, t + 4) * D + lane];
            float a5 = h[__shfl(my, t + 5) * D + lane];
            float a6 = h[__shfl(my, t + 6) * D + lane];
            float a7 = h[__shfl(my, t + 7) * D + lane];
            acc += ((a0 + a1) + (a2 + a3)) + ((a4 + a5) + (a6 + a7));
        }
        for (; t < m; ++t) acc += h[__shfl(my, t) * D + lane];
    }
    float vv = acc * rsqrtf((float)(cnt + 1));
    out[n * D + lane] = vv > 0.0f ? vv : 0.01f * vv;
}

// ---------------------------------------------------------------------------
extern "C" void kernel_launch(void* const* d_in, const int* in_sizes, int n_in,
                              void* d_out, int out_size, void* d_ws, size_t ws_size,
                              hipStream_t stream) {
    const float* x       = (const float*)d_in[0];
    const int*   senders = (const int*)d_in[1];
    const int*   recvs   = (const int*)d_in[2];
    const float* weight  = (const float*)d_in[3];
    const float* bias    = (const float*)d_in[4];
    float* out = (float*)d_out;

    // workspace layout (256B-aligned chunks)
    char* p = (char*)d_ws;
    auto take = [&](size_t bytes) { char* q = p; p += (bytes + 255) & ~(size_t)255; return q; };
    float*         h      = (float*)take((size_t)N_NODES * D * 4);      // 12.8 MB
    float*         sscale = (float*)take((size_t)N_NODES * 4);          // 200 KB
    unsigned*      pr     = (unsigned*)take((size_t)N_EDGES * 4);       // 3.2 MB
    unsigned char* ps8    = (unsigned char*)take((size_t)N_EDGES);      // 0.8 MB
    int*           rcnt   = (int*)take((size_t)SCAN_N * 4);             // 150 KB
    int*           scnt   = (int*)take((size_t)SCAN_N * 4);             // 150 KB
    int*           rowoff = (int*)take((size_t)(N_NODES + 1) * 4);      // 200 KB
    ushort*        csr16  = (ushort*)take((size_t)N_EDGES * 2);         // 1.6 MB

    hipLaunchKernelGGL(count_kernel, dim3(NSLICE), dim3(1024), 0, stream,
                       senders, recvs, rcnt, scnt);
    hipLaunchKernelGGL(scan_kernel, dim3(1), dim3(1024), 0, stream, rcnt, scnt);
    hipLaunchKernelGGL(part_kernel, dim3(NSLICE), dim3(1024), 0, stream,
                       senders, recvs, rcnt, scnt, pr, ps8);
    hipLaunchKernelGGL(sscale_kernel, dim3(NB), dim3(BSZ), 0, stream,
                       scnt, ps8, sscale);
    hipLaunchKernelGGL(csr_kernel, dim3(NB), dim3(BSZ), 0, stream,
                       pr, rcnt, rowoff, csr16);
    hipLaunchKernelGGL(linear_kernel, dim3(1024), dim3(256), 0, stream,
                       x, weight, bias, sscale, h);
    hipLaunchKernelGGL(gather_kernel, dim3((N_NODES + 3) / 4), dim3(256), 0, stream,
                       h, rowoff, csr16, out);
}

// Round 7
// 111.683 us; speedup vs baseline: 4.9311x; 2.0960x over previous
//
#include <hip/hip_runtime.h>

#define N_NODES 50000
#define N_EDGES 800000
#define D 64
#define NB 196            // buckets; 196*256 = 50176 >= 50000 (bucket = id >> 8)
#define BSZ 256           // nodes per bucket
#define NSLICE 196        // edge slices; 196*4096 = 802816 >= 800000
#define E4 (N_EDGES / 4)  // 200000 int4 groups

// ---------------------------------------------------------------------------
// K1: per-slice bucket histograms (receiver and sender). No global atomics.
// cnt layout: [bucket][slice].
// ---------------------------------------------------------------------------
__global__ __launch_bounds__(1024) void count_kernel(
        const int* __restrict__ s, const int* __restrict__ r,
        int* __restrict__ rcnt, int* __restrict__ scnt) {
    __shared__ int rh[NB], sh[NB];
    const int tid = threadIdx.x, sl = blockIdx.x;
    for (int i = tid; i < NB; i += 1024) { rh[i] = 0; sh[i] = 0; }
    __syncthreads();

    int e4 = sl * 1024 + tid;
    if (e4 < E4) {
        int4 rv = ((const int4*)r)[e4];
        int4 sv = ((const int4*)s)[e4];
        atomicAdd(&rh[rv.x >> 8], 1); atomicAdd(&rh[rv.y >> 8], 1);
        atomicAdd(&rh[rv.z >> 8], 1); atomicAdd(&rh[rv.w >> 8], 1);
        atomicAdd(&sh[sv.x >> 8], 1); atomicAdd(&sh[sv.y >> 8], 1);
        atomicAdd(&sh[sv.z >> 8], 1); atomicAdd(&sh[sv.w >> 8], 1);
    }
    __syncthreads();
    for (int i = tid; i < NB; i += 1024) {
        rcnt[i * NSLICE + sl] = rh[i];
        scnt[i * NSLICE + sl] = sh[i];
    }
}

// ---------------------------------------------------------------------------
// K2a: per-bucket scan of slice counts (392 blocks: [0,NB)=rcnt, [NB,2NB)=scnt).
// In-place exclusive prefix within the bucket; bucket total -> tot[b].
// ---------------------------------------------------------------------------
__global__ __launch_bounds__(256) void scanA_kernel(
        int* __restrict__ rcnt, int* __restrict__ scnt,
        int* __restrict__ rtot, int* __restrict__ stot) {
    __shared__ int sc[256];
    const int tid = threadIdx.x;
    const int b = blockIdx.x;
    int* arr = (b < NB) ? rcnt : scnt;
    int* tot = (b < NB) ? rtot : stot;
    const int bb = (b < NB) ? b : b - NB;

    int v = (tid < NSLICE) ? arr[bb * NSLICE + tid] : 0;
    sc[tid] = v;
    __syncthreads();
    for (int o = 1; o < 256; o <<= 1) {
        int u = (tid >= o) ? sc[tid - o] : 0;
        __syncthreads();
        sc[tid] += u;
        __syncthreads();
    }
    if (tid < NSLICE) arr[bb * NSLICE + tid] = sc[tid] - v;  // exclusive
    if (tid == 255) tot[bb] = sc[255];
}

// ---------------------------------------------------------------------------
// K2b: exclusive scan of the 196 bucket totals (both arrays). Tiny.
// base[NB] sentinel = N_EDGES.
// ---------------------------------------------------------------------------
__global__ __launch_bounds__(256) void scanB_kernel(
        const int* __restrict__ rtot, const int* __restrict__ stot,
        int* __restrict__ rbase, int* __restrict__ sbase) {
    __shared__ int sc[256];
    const int tid = threadIdx.x;
    for (int pass = 0; pass < 2; ++pass) {
        const int* tot = pass ? stot : rtot;
        int* base = pass ? sbase : rbase;
        int v = (tid < NB) ? tot[tid] : 0;
        sc[tid] = v;
        __syncthreads();
        for (int o = 1; o < 256; o <<= 1) {
            int u = (tid >= o) ? sc[tid - o] : 0;
            __syncthreads();
            sc[tid] += u;
            __syncthreads();
        }
        if (tid < NB) base[tid] = sc[tid] - v;
        if (tid == 0) base[NB] = N_EDGES;
        __syncthreads();
    }
}

// ---------------------------------------------------------------------------
// K3: radix partition. Receiver-bucketed packed pairs (rl<<16 | s) and
// sender-bucketed local ids (u8). LDS cursor atomics only.
// ---------------------------------------------------------------------------
__global__ __launch_bounds__(1024) void part_kernel(
        const int* __restrict__ s, const int* __restrict__ r,
        const int* __restrict__ rcnt, const int* __restrict__ scnt,
        const int* __restrict__ rbase, const int* __restrict__ sbase,
        unsigned* __restrict__ pr, unsigned char* __restrict__ ps8) {
    __shared__ int rcur[NB], scur[NB];
    const int tid = threadIdx.x, sl = blockIdx.x;
    for (int i = tid; i < NB; i += 1024) {
        rcur[i] = rbase[i] + rcnt[i * NSLICE + sl];
        scur[i] = sbase[i] + scnt[i * NSLICE + sl];
    }
    __syncthreads();

    int e4 = sl * 1024 + tid;
    if (e4 < E4) {
        int4 rv = ((const int4*)r)[e4];
        int4 sv = ((const int4*)s)[e4];
        int ri[4] = {rv.x, rv.y, rv.z, rv.w};
        int si[4] = {sv.x, sv.y, sv.z, sv.w};
        #pragma unroll
        for (int k = 0; k < 4; ++k) {
            int pos = atomicAdd(&rcur[ri[k] >> 8], 1);
            pr[pos] = ((unsigned)(ri[k] & 255) << 16) | (unsigned)si[k];
            int pos2 = atomicAdd(&scur[si[k] >> 8], 1);
            ps8[pos2] = (unsigned char)(si[k] & 255);
        }
    }
}

// ---------------------------------------------------------------------------
// K4: node-level sender degree from the u8 partition -> sscale.
// ---------------------------------------------------------------------------
__global__ __launch_bounds__(256) void sscale_kernel(
        const int* __restrict__ sbase, const unsigned char* __restrict__ ps8,
        float* __restrict__ sscale) {
    __shared__ int hist[BSZ];
    const int b = blockIdx.x, tid = threadIdx.x;
    hist[tid] = 0;
    __syncthreads();
    const int sb = sbase[b], se = sbase[b + 1];
    for (int i = sb + tid; i < se; i += 256) atomicAdd(&hist[ps8[i]], 1);
    __syncthreads();
    int n = b * BSZ + tid;
    if (n < N_NODES) sscale[n] = rsqrtf((float)(hist[tid] + 1));  // +1 self edge
}

// ---------------------------------------------------------------------------
// K5: per-bucket CSR finalize: node hist + LDS scan -> rowoff, then
// cursor-scatter senders (u16) into per-node csr16. LDS atomics only.
// ---------------------------------------------------------------------------
__global__ __launch_bounds__(256) void csr_kernel(
        const unsigned* __restrict__ pr, const int* __restrict__ rbase,
        int* __restrict__ rowoff, ushort* __restrict__ csr16) {
    __shared__ int hist[BSZ];
    __shared__ int cur[BSZ];
    const int b = blockIdx.x, tid = threadIdx.x;
    const int rb = rbase[b], re = rbase[b + 1];

    hist[tid] = 0;
    __syncthreads();
    for (int i = rb + tid; i < re; i += 256)
        atomicAdd(&hist[pr[i] >> 16], 1);
    __syncthreads();

    int v = hist[tid];
    __syncthreads();
    hist[tid] = v;
    __syncthreads();
    for (int o = 1; o < 256; o <<= 1) {
        int u = (tid >= o) ? hist[tid - o] : 0;
        __syncthreads();
        hist[tid] += u;
        __syncthreads();
    }
    int excl = hist[tid] - v;
    int n = b * BSZ + tid;
    if (n < N_NODES) rowoff[n] = rb + excl;
    cur[tid] = rb + excl;
    if (b == NB - 1 && tid == 0) rowoff[N_NODES] = N_EDGES;
    __syncthreads();

    for (int i = rb + tid; i < re; i += 256) {
        unsigned pw = pr[i];
        int pos = atomicAdd(&cur[pw >> 16], 1);
        csr16[pos] = (ushort)(pw & 0xffffu);
    }
}

// ---------------------------------------------------------------------------
// K6: h = (x @ W^T + b) * sscale[n]. Wave per node, lane = out channel.
// ---------------------------------------------------------------------------
__global__ __launch_bounds__(256) void linear_kernel(
        const float* __restrict__ x, const float* __restrict__ w,
        const float* __restrict__ bias, const float* __restrict__ sscale,
        float* __restrict__ h) {
    const int lane = threadIdx.x & 63;
    const int wid = blockIdx.x * 4 + (threadIdx.x >> 6);
    const int nwaves = gridDim.x * 4;

    float4 wreg[16];
    #pragma unroll
    for (int i = 0; i < 16; ++i) wreg[i] = ((const float4*)w)[lane * 16 + i];
    const float bo = bias[lane];

    for (int n = wid; n < N_NODES; n += nwaves) {
        const float4* xr = (const float4*)(x + n * D);
        float a0 = 0.f, a1 = 0.f, a2 = 0.f, a3 = 0.f;
        #pragma unroll
        for (int i = 0; i < 16; i += 4) {
            float4 x0 = xr[i], x1 = xr[i + 1], x2 = xr[i + 2], x3 = xr[i + 3];
            a0 += x0.x * wreg[i].x + x0.y * wreg[i].y + x0.z * wreg[i].z + x0.w * wreg[i].w;
            a1 += x1.x * wreg[i+1].x + x1.y * wreg[i+1].y + x1.z * wreg[i+1].z + x1.w * wreg[i+1].w;
            a2 += x2.x * wreg[i+2].x + x2.y * wreg[i+2].y + x2.z * wreg[i+2].z + x2.w * wreg[i+2].w;
            a3 += x3.x * wreg[i+3].x + x3.y * wreg[i+3].y + x3.z * wreg[i+3].z + x3.w * wreg[i+3].w;
        }
        h[n * D + lane] = (bo + (a0 + a1) + (a2 + a3)) * sscale[n];
    }
}

// ---------------------------------------------------------------------------
// K7: gather-accumulate per receiver + self-term + rsqrt + leaky-relu.
// Wave per node (12500 blocks -> full occupancy), 8-deep load batching.
// ---------------------------------------------------------------------------
__global__ __launch_bounds__(256) void gather_kernel(
        const float* __restrict__ h, const int* __restrict__ rowoff,
        const ushort* __restrict__ csr16, float* __restrict__ out) {
    const int lane = threadIdx.x & 63;
    const int n = blockIdx.x * 4 + (threadIdx.x >> 6);
    if (n >= N_NODES) return;

    float acc = h[n * D + lane];           // self-edge contribution
    const int base = rowoff[n];
    const int cnt = rowoff[n + 1] - base;

    for (int j0 = 0; j0 < cnt; j0 += 64) {
        int m = cnt - j0; if (m > 64) m = 64;
        int my = (lane < m) ? (int)csr16[base + j0 + lane] : 0;
        int t = 0;
        for (; t + 8 <= m; t += 8) {
            float a0 = h[__shfl(my, t + 0) * D + lane];
            float a1 = h[__shfl(my, t + 1) * D + lane];
            float a2 = h[__shfl(my, t + 2) * D + lane];
            float a3 = h[__shfl(my, t + 3) * D + lane];
            float a4 = h[__shfl(my, t + 4) * D + lane];
            float a5 = h[__shfl(my, t + 5) * D + lane];
            float a6 = h[__shfl(my, t + 6) * D + lane];
            float a7 = h[__shfl(my, t + 7) * D + lane];
            acc += ((a0 + a1) + (a2 + a3)) + ((a4 + a5) + (a6 + a7));
        }
        for (; t < m; ++t) acc += h[__shfl(my, t) * D + lane];
    }
    float vv = acc * rsqrtf((float)(cnt + 1));
    out[n * D + lane] = vv > 0.0f ? vv : 0.01f * vv;
}

// ---------------------------------------------------------------------------
extern "C" void kernel_launch(void* const* d_in, const int* in_sizes, int n_in,
                              void* d_out, int out_size, void* d_ws, size_t ws_size,
                              hipStream_t stream) {
    const float* x       = (const float*)d_in[0];
    const int*   senders = (const int*)d_in[1];
    const int*   recvs   = (const int*)d_in[2];
    const float* weight  = (const float*)d_in[3];
    const float* bias    = (const float*)d_in[4];
    float* out = (float*)d_out;

    // workspace layout (256B-aligned chunks)
    char* p = (char*)d_ws;
    auto take = [&](size_t bytes) { char* q = p; p += (bytes + 255) & ~(size_t)255; return q; };
    float*         h      = (float*)take((size_t)N_NODES * D * 4);      // 12.8 MB
    float*         sscale = (float*)take((size_t)N_NODES * 4);          // 200 KB
    unsigned*      pr     = (unsigned*)take((size_t)N_EDGES * 4);       // 3.2 MB
    unsigned char* ps8    = (unsigned char*)take((size_t)N_EDGES);      // 0.8 MB
    int*           rcnt   = (int*)take((size_t)NB * NSLICE * 4);        // 150 KB
    int*           scnt   = (int*)take((size_t)NB * NSLICE * 4);        // 150 KB
    int*           rtot   = (int*)take((size_t)NB * 4);
    int*           stot   = (int*)take((size_t)NB * 4);
    int*           rbase  = (int*)take((size_t)(NB + 1) * 4);
    int*           sbase  = (int*)take((size_t)(NB + 1) * 4);
    int*           rowoff = (int*)take((size_t)(N_NODES + 1) * 4);      // 200 KB
    ushort*        csr16  = (ushort*)take((size_t)N_EDGES * 2);         // 1.6 MB

    hipLaunchKernelGGL(count_kernel, dim3(NSLICE), dim3(1024), 0, stream,
                       senders, recvs, rcnt, scnt);
    hipLaunchKernelGGL(scanA_kernel, dim3(2 * NB), dim3(256), 0, stream,
                       rcnt, scnt, rtot, stot);
    hipLaunchKernelGGL(scanB_kernel, dim3(1), dim3(256), 0, stream,
                       rtot, stot, rbase, sbase);
    hipLaunchKernelGGL(part_kernel, dim3(NSLICE), dim3(1024), 0, stream,
                       senders, recvs, rcnt, scnt, rbase, sbase, pr, ps8);
    hipLaunchKernelGGL(sscale_kernel, dim3(NB), dim3(BSZ), 0, stream,
                       sbase, ps8, sscale);
    hipLaunchKernelGGL(csr_kernel, dim3(NB), dim3(BSZ), 0, stream,
                       pr, rbase, rowoff, csr16);
    hipLaunchKernelGGL(linear_kernel, dim3(1024), dim3(256), 0, stream,
                       x, weight, bias, sscale, h);
    hipLaunchKernelGGL(gather_kernel, dim3((N_NODES + 3) / 4), dim3(256), 0, stream,
                       h, rowoff, csr16, out);
}

// Round 8
// 109.894 us; speedup vs baseline: 5.0114x; 1.0163x over previous
//
#include <hip/hip_runtime.h>

#define N_NODES 50000
#define N_EDGES 800000
#define D 64
#define NB 196            // buckets; 196*256 = 50176 >= 50000 (bucket = id >> 8)
#define BSZ 256           // nodes per bucket
#define NSLICE 196        // edge slices; 196*4096 = 802816 >= 800000
#define E4 (N_EDGES / 4)  // 200000 int4 groups

// ---------------------------------------------------------------------------
// K1: per-slice bucket histograms (receiver and sender). No global atomics.
// cnt layout: [bucket][slice].
// ---------------------------------------------------------------------------
__global__ __launch_bounds__(1024) void count_kernel(
        const int* __restrict__ s, const int* __restrict__ r,
        int* __restrict__ rcnt, int* __restrict__ scnt) {
    __shared__ int rh[NB], sh[NB];
    const int tid = threadIdx.x, sl = blockIdx.x;
    for (int i = tid; i < NB; i += 1024) { rh[i] = 0; sh[i] = 0; }
    __syncthreads();

    int e4 = sl * 1024 + tid;
    if (e4 < E4) {
        int4 rv = ((const int4*)r)[e4];
        int4 sv = ((const int4*)s)[e4];
        atomicAdd(&rh[rv.x >> 8], 1); atomicAdd(&rh[rv.y >> 8], 1);
        atomicAdd(&rh[rv.z >> 8], 1); atomicAdd(&rh[rv.w >> 8], 1);
        atomicAdd(&sh[sv.x >> 8], 1); atomicAdd(&sh[sv.y >> 8], 1);
        atomicAdd(&sh[sv.z >> 8], 1); atomicAdd(&sh[sv.w >> 8], 1);
    }
    __syncthreads();
    for (int i = tid; i < NB; i += 1024) {
        rcnt[i * NSLICE + sl] = rh[i];
        scnt[i * NSLICE + sl] = sh[i];
    }
}

// ---------------------------------------------------------------------------
// K2a: per-bucket scan of slice counts (392 blocks: [0,NB)=rcnt, [NB,2NB)=scnt).
// ---------------------------------------------------------------------------
__global__ __launch_bounds__(256) void scanA_kernel(
        int* __restrict__ rcnt, int* __restrict__ scnt,
        int* __restrict__ rtot, int* __restrict__ stot) {
    __shared__ int sc[256];
    const int tid = threadIdx.x;
    const int b = blockIdx.x;
    int* arr = (b < NB) ? rcnt : scnt;
    int* tot = (b < NB) ? rtot : stot;
    const int bb = (b < NB) ? b : b - NB;

    int v = (tid < NSLICE) ? arr[bb * NSLICE + tid] : 0;
    sc[tid] = v;
    __syncthreads();
    for (int o = 1; o < 256; o <<= 1) {
        int u = (tid >= o) ? sc[tid - o] : 0;
        __syncthreads();
        sc[tid] += u;
        __syncthreads();
    }
    if (tid < NSLICE) arr[bb * NSLICE + tid] = sc[tid] - v;  // exclusive
    if (tid == 255) tot[bb] = sc[255];
}

// ---------------------------------------------------------------------------
// K2b: exclusive scan of the 196 bucket totals (both arrays). Tiny.
// ---------------------------------------------------------------------------
__global__ __launch_bounds__(256) void scanB_kernel(
        const int* __restrict__ rtot, const int* __restrict__ stot,
        int* __restrict__ rbase, int* __restrict__ sbase) {
    __shared__ int sc[256];
    const int tid = threadIdx.x;
    for (int pass = 0; pass < 2; ++pass) {
        const int* tot = pass ? stot : rtot;
        int* base = pass ? sbase : rbase;
        int v = (tid < NB) ? tot[tid] : 0;
        sc[tid] = v;
        __syncthreads();
        for (int o = 1; o < 256; o <<= 1) {
            int u = (tid >= o) ? sc[tid - o] : 0;
            __syncthreads();
            sc[tid] += u;
            __syncthreads();
        }
        if (tid < NB) base[tid] = sc[tid] - v;
        if (tid == 0) base[NB] = N_EDGES;
        __syncthreads();
    }
}

// ---------------------------------------------------------------------------
// K3: radix partition. Receiver-bucketed packed pairs (rl<<16 | s) and
// sender-bucketed local ids (u8). LDS cursor atomics only.
// ---------------------------------------------------------------------------
__global__ __launch_bounds__(1024) void part_kernel(
        const int* __restrict__ s, const int* __restrict__ r,
        const int* __restrict__ rcnt, const int* __restrict__ scnt,
        const int* __restrict__ rbase, const int* __restrict__ sbase,
        unsigned* __restrict__ pr, unsigned char* __restrict__ ps8) {
    __shared__ int rcur[NB], scur[NB];
    const int tid = threadIdx.x, sl = blockIdx.x;
    for (int i = tid; i < NB; i += 1024) {
        rcur[i] = rbase[i] + rcnt[i * NSLICE + sl];
        scur[i] = sbase[i] + scnt[i * NSLICE + sl];
    }
    __syncthreads();

    int e4 = sl * 1024 + tid;
    if (e4 < E4) {
        int4 rv = ((const int4*)r)[e4];
        int4 sv = ((const int4*)s)[e4];
        int ri[4] = {rv.x, rv.y, rv.z, rv.w};
        int si[4] = {sv.x, sv.y, sv.z, sv.w};
        #pragma unroll
        for (int k = 0; k < 4; ++k) {
            int pos = atomicAdd(&rcur[ri[k] >> 8], 1);
            pr[pos] = ((unsigned)(ri[k] & 255) << 16) | (unsigned)si[k];
            int pos2 = atomicAdd(&scur[si[k] >> 8], 1);
            ps8[pos2] = (unsigned char)(si[k] & 255);
        }
    }
}

// ---------------------------------------------------------------------------
// K4: node-level sender degree from the u8 partition -> sscale.
// ---------------------------------------------------------------------------
__global__ __launch_bounds__(256) void sscale_kernel(
        const int* __restrict__ sbase, const unsigned char* __restrict__ ps8,
        float* __restrict__ sscale) {
    __shared__ int hist[BSZ];
    const int b = blockIdx.x, tid = threadIdx.x;
    hist[tid] = 0;
    __syncthreads();
    const int sb = sbase[b], se = sbase[b + 1];
    for (int i = sb + tid; i < se; i += 256) atomicAdd(&hist[ps8[i]], 1);
    __syncthreads();
    int n = b * BSZ + tid;
    if (n < N_NODES) sscale[n] = rsqrtf((float)(hist[tid] + 1));  // +1 self edge
}

// ---------------------------------------------------------------------------
// K5: per-bucket CSR finalize: node hist + LDS scan -> rowoff, then
// cursor-scatter senders (u16) into per-node csr16. LDS atomics only.
// ---------------------------------------------------------------------------
__global__ __launch_bounds__(256) void csr_kernel(
        const unsigned* __restrict__ pr, const int* __restrict__ rbase,
        int* __restrict__ rowoff, ushort* __restrict__ csr16) {
    __shared__ int hist[BSZ];
    __shared__ int cur[BSZ];
    const int b = blockIdx.x, tid = threadIdx.x;
    const int rb = rbase[b], re = rbase[b + 1];

    hist[tid] = 0;
    __syncthreads();
    for (int i = rb + tid; i < re; i += 256)
        atomicAdd(&hist[pr[i] >> 16], 1);
    __syncthreads();

    int v = hist[tid];
    __syncthreads();
    hist[tid] = v;
    __syncthreads();
    for (int o = 1; o < 256; o <<= 1) {
        int u = (tid >= o) ? hist[tid - o] : 0;
        __syncthreads();
        hist[tid] += u;
        __syncthreads();
    }
    int excl = hist[tid] - v;
    int n = b * BSZ + tid;
    if (n < N_NODES) rowoff[n] = rb + excl;
    cur[tid] = rb + excl;
    if (b == NB - 1 && tid == 0) rowoff[N_NODES] = N_EDGES;
    __syncthreads();

    for (int i = rb + tid; i < re; i += 256) {
        unsigned pw = pr[i];
        int pos = atomicAdd(&cur[pw >> 16], 1);
        csr16[pos] = (ushort)(pw & 0xffffu);
    }
}

// ---------------------------------------------------------------------------
// K6: h = (x @ W^T + b) * sscale[n]. LDS-tiled: block owns 64 nodes;
// W (rows padded to 68 floats -> 4-bank stagger) + x tile in LDS; thread
// computes a 4-node x 4-output register tile (1024 FMA : 128 ds_read_b128).
// ---------------------------------------------------------------------------
__global__ __launch_bounds__(256) void linear_kernel(
        const float* __restrict__ x, const float* __restrict__ w,
        const float* __restrict__ bias, const float* __restrict__ sscale,
        float* __restrict__ h) {
    __shared__ float wlds[64 * 68];
    __shared__ float xlds[64 * 68];
    __shared__ float blds[64];
    __shared__ float slds[64];
    const int t = threadIdx.x;
    const int t15 = t & 15;
    const int g = t >> 4;           // 0..15: node group (4 nodes each)
    const int nb = blockIdx.x * 64;

    #pragma unroll
    for (int q = 0; q < 4; ++q) {   // stage W: 1024 float4
        int idx = q * 256 + t;
        int o = idx >> 4, k4 = idx & 15;
        float4 wv = ((const float4*)w)[idx];
        *(float4*)&wlds[o * 68 + k4 * 4] = wv;
    }
    if (t < 64) {
        blds[t] = bias[t];
        int n = nb + t;
        slds[t] = (n < N_NODES) ? sscale[n] : 0.f;
    }
    #pragma unroll
    for (int q = 0; q < 4; ++q) {   // stage x tile: 64 nodes x 16 float4
        int idx = q * 256 + t;
        int nl = idx >> 4, k4 = idx & 15;
        int n = nb + nl;
        float4 xv = (n < N_NODES) ? ((const float4*)x)[n * 16 + k4]
                                  : make_float4(0.f, 0.f, 0.f, 0.f);
        *(float4*)&xlds[nl * 68 + k4 * 4] = xv;
    }
    __syncthreads();

    float acc[4][4];
    #pragma unroll
    for (int i = 0; i < 4; ++i)
        #pragma unroll
        for (int j = 0; j < 4; ++j) acc[i][j] = 0.f;

    #pragma unroll
    for (int k4 = 0; k4 < 16; ++k4) {
        float4 wv0 = *(const float4*)&wlds[(t15     ) * 68 + k4 * 4];
        float4 wv1 = *(const float4*)&wlds[(t15 + 16) * 68 + k4 * 4];
        float4 wv2 = *(const float4*)&wlds[(t15 + 32) * 68 + k4 * 4];
        float4 wv3 = *(const float4*)&wlds[(t15 + 48) * 68 + k4 * 4];
        #pragma unroll
        for (int i = 0; i < 4; ++i) {
            float4 xv = *(const float4*)&xlds[(g * 4 + i) * 68 + k4 * 4];
            acc[i][0] += xv.x * wv0.x + xv.y * wv0.y + xv.z * wv0.z + xv.w * wv0.w;
            acc[i][1] += xv.x * wv1.x + xv.y * wv1.y + xv.z * wv1.z + xv.w * wv1.w;
            acc[i][2] += xv.x * wv2.x + xv.y * wv2.y + xv.z * wv2.z + xv.w * wv2.w;
            acc[i][3] += xv.x * wv3.x + xv.y * wv3.y + xv.z * wv3.z + xv.w * wv3.w;
        }
    }

    #pragma unroll
    for (int i = 0; i < 4; ++i) {
        int nl = g * 4 + i;
        int n = nb + nl;
        if (n < N_NODES) {
            float sc = slds[nl];
            h[n * D + t15     ] = (acc[i][0] + blds[t15     ]) * sc;
            h[n * D + t15 + 16] = (acc[i][1] + blds[t15 + 16]) * sc;
            h[n * D + t15 + 32] = (acc[i][2] + blds[t15 + 32]) * sc;
            h[n * D + t15 + 48] = (acc[i][3] + blds[t15 + 48]) * sc;
        }
    }
}

// ---------------------------------------------------------------------------
// K7: gather-accumulate per receiver + self-term + rsqrt + leaky-relu.
// Wave per node (12500 blocks -> full occupancy), 8-deep load batching.
// ---------------------------------------------------------------------------
__global__ __launch_bounds__(256) void gather_kernel(
        const float* __restrict__ h, const int* __restrict__ rowoff,
        const ushort* __restrict__ csr16, float* __restrict__ out) {
    const int lane = threadIdx.x & 63;
    const int n = blockIdx.x * 4 + (threadIdx.x >> 6);
    if (n >= N_NODES) return;

    float acc = h[n * D + lane];           // self-edge contribution
    const int base = rowoff[n];
    const int cnt = rowoff[n + 1] - base;

    for (int j0 = 0; j0 < cnt; j0 += 64) {
        int m = cnt - j0; if (m > 64) m = 64;
        int my = (lane < m) ? (int)csr16[base + j0 + lane] : 0;
        int t = 0;
        for (; t + 8 <= m; t += 8) {
            float a0 = h[__shfl(my, t + 0) * D + lane];
            float a1 = h[__shfl(my, t + 1) * D + lane];
            float a2 = h[__shfl(my, t + 2) * D + lane];
            float a3 = h[__shfl(my, t + 3) * D + lane];
            float a4 = h[__shfl(my, t + 4) * D + lane];
            float a5 = h[__shfl(my, t + 5) * D + lane];
            float a6 = h[__shfl(my, t + 6) * D + lane];
            float a7 = h[__shfl(my, t + 7) * D + lane];
            acc += ((a0 + a1) + (a2 + a3)) + ((a4 + a5) + (a6 + a7));
        }
        for (; t < m; ++t) acc += h[__shfl(my, t) * D + lane];
    }
    float vv = acc * rsqrtf((float)(cnt + 1));
    out[n * D + lane] = vv > 0.0f ? vv : 0.01f * vv;
}

// ---------------------------------------------------------------------------
extern "C" void kernel_launch(void* const* d_in, const int* in_sizes, int n_in,
                              void* d_out, int out_size, void* d_ws, size_t ws_size,
                              hipStream_t stream) {
    const float* x       = (const float*)d_in[0];
    const int*   senders = (const int*)d_in[1];
    const int*   recvs   = (const int*)d_in[2];
    const float* weight  = (const float*)d_in[3];
    const float* bias    = (const float*)d_in[4];
    float* out = (float*)d_out;

    // workspace layout (256B-aligned chunks)
    char* p = (char*)d_ws;
    auto take = [&](size_t bytes) { char* q = p; p += (bytes + 255) & ~(size_t)255; return q; };
    float*         h      = (float*)take((size_t)N_NODES * D * 4);      // 12.8 MB
    float*         sscale = (float*)take((size_t)N_NODES * 4);          // 200 KB
    unsigned*      pr     = (unsigned*)take((size_t)N_EDGES * 4);       // 3.2 MB
    unsigned char* ps8    = (unsigned char*)take((size_t)N_EDGES);      // 0.8 MB
    int*           rcnt   = (int*)take((size_t)NB * NSLICE * 4);        // 150 KB
    int*           scnt   = (int*)take((size_t)NB * NSLICE * 4);        // 150 KB
    int*           rtot   = (int*)take((size_t)NB * 4);
    int*           stot   = (int*)take((size_t)NB * 4);
    int*           rbase  = (int*)take((size_t)(NB + 1) * 4);
    int*           sbase  = (int*)take((size_t)(NB + 1) * 4);
    int*           rowoff = (int*)take((size_t)(N_NODES + 1) * 4);      // 200 KB
    ushort*        csr16  = (ushort*)take((size_t)N_EDGES * 2);         // 1.6 MB

    hipLaunchKernelGGL(count_kernel, dim3(NSLICE), dim3(1024), 0, stream,
                       senders, recvs, rcnt, scnt);
    hipLaunchKernelGGL(scanA_kernel, dim3(2 * NB), dim3(256), 0, stream,
                       rcnt, scnt, rtot, stot);
    hipLaunchKernelGGL(scanB_kernel, dim3(1), dim3(256), 0, stream,
                       rtot, stot, rbase, sbase);
    hipLaunchKernelGGL(part_kernel, dim3(NSLICE), dim3(1024), 0, stream,
                       senders, recvs, rcnt, scnt, rbase, sbase, pr, ps8);
    hipLaunchKernelGGL(sscale_kernel, dim3(NB), dim3(BSZ), 0, stream,
                       sbase, ps8, sscale);
    hipLaunchKernelGGL(csr_kernel, dim3(NB), dim3(BSZ), 0, stream,
                       pr, rbase, rowoff, csr16);
    hipLaunchKernelGGL(linear_kernel, dim3((N_NODES + 63) / 64), dim3(256), 0, stream,
                       x, weight, bias, sscale, h);
    hipLaunchKernelGGL(gather_kernel, dim3((N_NODES + 3) / 4), dim3(256), 0, stream,
                       h, rowoff, csr16, out);
}

// Round 9
// 89.763 us; speedup vs baseline: 6.1353x; 1.2243x over previous
//
#include <hip/hip_runtime.h>

#define N_NODES 50000
#define N_EDGES 800000
#define D 64
#define NB 196            // buckets; 196*256 = 50176 >= 50000 (bucket = id >> 8)
#define BSZ 256           // nodes per bucket
#define NSLICE 196        // edge slices; 196*4096 = 802816 >= 800000
#define E4 (N_EDGES / 4)  // 200000 int4 groups

// ---------------------------------------------------------------------------
// K1: per-slice bucket histograms (receiver and sender). No global atomics.
// ---------------------------------------------------------------------------
__global__ __launch_bounds__(1024) void count_kernel(
        const int* __restrict__ s, const int* __restrict__ r,
        int* __restrict__ rcnt, int* __restrict__ scnt) {
    __shared__ int rh[NB], sh[NB];
    const int tid = threadIdx.x, sl = blockIdx.x;
    for (int i = tid; i < NB; i += 1024) { rh[i] = 0; sh[i] = 0; }
    __syncthreads();

    int e4 = sl * 1024 + tid;
    if (e4 < E4) {
        int4 rv = ((const int4*)r)[e4];
        int4 sv = ((const int4*)s)[e4];
        atomicAdd(&rh[rv.x >> 8], 1); atomicAdd(&rh[rv.y >> 8], 1);
        atomicAdd(&rh[rv.z >> 8], 1); atomicAdd(&rh[rv.w >> 8], 1);
        atomicAdd(&sh[sv.x >> 8], 1); atomicAdd(&sh[sv.y >> 8], 1);
        atomicAdd(&sh[sv.z >> 8], 1); atomicAdd(&sh[sv.w >> 8], 1);
    }
    __syncthreads();
    for (int i = tid; i < NB; i += 1024) {
        rcnt[i * NSLICE + sl] = rh[i];
        scnt[i * NSLICE + sl] = sh[i];
    }
}

// ---------------------------------------------------------------------------
// K2a: per-bucket scan of slice counts (392 blocks).
// ---------------------------------------------------------------------------
__global__ __launch_bounds__(256) void scanA_kernel(
        int* __restrict__ rcnt, int* __restrict__ scnt,
        int* __restrict__ rtot, int* __restrict__ stot) {
    __shared__ int sc[256];
    const int tid = threadIdx.x;
    const int b = blockIdx.x;
    int* arr = (b < NB) ? rcnt : scnt;
    int* tot = (b < NB) ? rtot : stot;
    const int bb = (b < NB) ? b : b - NB;

    int v = (tid < NSLICE) ? arr[bb * NSLICE + tid] : 0;
    sc[tid] = v;
    __syncthreads();
    for (int o = 1; o < 256; o <<= 1) {
        int u = (tid >= o) ? sc[tid - o] : 0;
        __syncthreads();
        sc[tid] += u;
        __syncthreads();
    }
    if (tid < NSLICE) arr[bb * NSLICE + tid] = sc[tid] - v;  // exclusive
    if (tid == 255) tot[bb] = sc[255];
}

// ---------------------------------------------------------------------------
// K2b: exclusive scan of the 196 bucket totals (both arrays). Tiny.
// ---------------------------------------------------------------------------
__global__ __launch_bounds__(256) void scanB_kernel(
        const int* __restrict__ rtot, const int* __restrict__ stot,
        int* __restrict__ rbase, int* __restrict__ sbase) {
    __shared__ int sc[256];
    const int tid = threadIdx.x;
    for (int pass = 0; pass < 2; ++pass) {
        const int* tot = pass ? stot : rtot;
        int* base = pass ? sbase : rbase;
        int v = (tid < NB) ? tot[tid] : 0;
        sc[tid] = v;
        __syncthreads();
        for (int o = 1; o < 256; o <<= 1) {
            int u = (tid >= o) ? sc[tid - o] : 0;
            __syncthreads();
            sc[tid] += u;
            __syncthreads();
        }
        if (tid < NB) base[tid] = sc[tid] - v;
        if (tid == 0) base[NB] = N_EDGES;
        __syncthreads();
    }
}

// ---------------------------------------------------------------------------
// K3: radix partition. LDS cursor atomics only.
// ---------------------------------------------------------------------------
__global__ __launch_bounds__(1024) void part_kernel(
        const int* __restrict__ s, const int* __restrict__ r,
        const int* __restrict__ rcnt, const int* __restrict__ scnt,
        const int* __restrict__ rbase, const int* __restrict__ sbase,
        unsigned* __restrict__ pr, unsigned char* __restrict__ ps8) {
    __shared__ int rcur[NB], scur[NB];
    const int tid = threadIdx.x, sl = blockIdx.x;
    for (int i = tid; i < NB; i += 1024) {
        rcur[i] = rbase[i] + rcnt[i * NSLICE + sl];
        scur[i] = sbase[i] + scnt[i * NSLICE + sl];
    }
    __syncthreads();

    int e4 = sl * 1024 + tid;
    if (e4 < E4) {
        int4 rv = ((const int4*)r)[e4];
        int4 sv = ((const int4*)s)[e4];
        int ri[4] = {rv.x, rv.y, rv.z, rv.w};
        int si[4] = {sv.x, sv.y, sv.z, sv.w};
        #pragma unroll
        for (int k = 0; k < 4; ++k) {
            int pos = atomicAdd(&rcur[ri[k] >> 8], 1);
            pr[pos] = ((unsigned)(ri[k] & 255) << 16) | (unsigned)si[k];
            int pos2 = atomicAdd(&scur[si[k] >> 8], 1);
            ps8[pos2] = (unsigned char)(si[k] & 255);
        }
    }
}

// ---------------------------------------------------------------------------
// K4: node-level sender degree from the u8 partition -> sscale.
// ---------------------------------------------------------------------------
__global__ __launch_bounds__(256) void sscale_kernel(
        const int* __restrict__ sbase, const unsigned char* __restrict__ ps8,
        float* __restrict__ sscale) {
    __shared__ int hist[BSZ];
    const int b = blockIdx.x, tid = threadIdx.x;
    hist[tid] = 0;
    __syncthreads();
    const int sb = sbase[b], se = sbase[b + 1];
    for (int i = sb + tid; i < se; i += 256) atomicAdd(&hist[ps8[i]], 1);
    __syncthreads();
    int n = b * BSZ + tid;
    if (n < N_NODES) sscale[n] = rsqrtf((float)(hist[tid] + 1));  // +1 self edge
}

// ---------------------------------------------------------------------------
// K5: per-bucket CSR finalize. LDS atomics only.
// ---------------------------------------------------------------------------
__global__ __launch_bounds__(256) void csr_kernel(
        const unsigned* __restrict__ pr, const int* __restrict__ rbase,
        int* __restrict__ rowoff, ushort* __restrict__ csr16) {
    __shared__ int hist[BSZ];
    __shared__ int cur[BSZ];
    const int b = blockIdx.x, tid = threadIdx.x;
    const int rb = rbase[b], re = rbase[b + 1];

    hist[tid] = 0;
    __syncthreads();
    for (int i = rb + tid; i < re; i += 256)
        atomicAdd(&hist[pr[i] >> 16], 1);
    __syncthreads();

    int v = hist[tid];
    __syncthreads();
    hist[tid] = v;
    __syncthreads();
    for (int o = 1; o < 256; o <<= 1) {
        int u = (tid >= o) ? hist[tid - o] : 0;
        __syncthreads();
        hist[tid] += u;
        __syncthreads();
    }
    int excl = hist[tid] - v;
    int n = b * BSZ + tid;
    if (n < N_NODES) rowoff[n] = rb + excl;
    cur[tid] = rb + excl;
    if (b == NB - 1 && tid == 0) rowoff[N_NODES] = N_EDGES;
    __syncthreads();

    for (int i = rb + tid; i < re; i += 256) {
        unsigned pw = pr[i];
        int pos = atomicAdd(&cur[pw >> 16], 1);
        csr16[pos] = (ushort)(pw & 0xffffu);
    }
}

// ---------------------------------------------------------------------------
// K6: h = (x @ W^T + b) * sscale[n]. LDS-tiled, register-pressure-capped:
// __launch_bounds__(256,4) caps VGPR<=128; unroll 2 on the K loop keeps the
// live ds_read window small (r8 post-mortem: full unroll hit the 256-VGPR
// clamp -> 1 wave/SIMD, 43.9us).
// ---------------------------------------------------------------------------
__global__ __launch_bounds__(256, 4) void linear_kernel(
        const float* __restrict__ x, const float* __restrict__ w,
        const float* __restrict__ bias, const float* __restrict__ sscale,
        float* __restrict__ h) {
    __shared__ float wlds[64 * 68];
    __shared__ float xlds[64 * 68];
    __shared__ float blds[64];
    __shared__ float slds[64];
    const int t = threadIdx.x;
    const int t15 = t & 15;
    const int g = t >> 4;           // 0..15: node group (4 nodes each)
    const int nb = blockIdx.x * 64;

    #pragma unroll
    for (int q = 0; q < 4; ++q) {   // stage W: 1024 float4
        int idx = q * 256 + t;
        int o = idx >> 4, k4 = idx & 15;
        float4 wv = ((const float4*)w)[idx];
        *(float4*)&wlds[o * 68 + k4 * 4] = wv;
    }
    if (t < 64) {
        blds[t] = bias[t];
        int n = nb + t;
        slds[t] = (n < N_NODES) ? sscale[n] : 0.f;
    }
    #pragma unroll
    for (int q = 0; q < 4; ++q) {   // stage x tile: 64 nodes x 16 float4
        int idx = q * 256 + t;
        int nl = idx >> 4, k4 = idx & 15;
        int n = nb + nl;
        float4 xv = (n < N_NODES) ? ((const float4*)x)[n * 16 + k4]
                                  : make_float4(0.f, 0.f, 0.f, 0.f);
        *(float4*)&xlds[nl * 68 + k4 * 4] = xv;
    }
    __syncthreads();

    float acc[4][4];
    #pragma unroll
    for (int i = 0; i < 4; ++i)
        #pragma unroll
        for (int j = 0; j < 4; ++j) acc[i][j] = 0.f;

    #pragma unroll 2
    for (int k4 = 0; k4 < 16; ++k4) {
        float4 wv0 = *(const float4*)&wlds[(t15     ) * 68 + k4 * 4];
        float4 wv1 = *(const float4*)&wlds[(t15 + 16) * 68 + k4 * 4];
        float4 wv2 = *(const float4*)&wlds[(t15 + 32) * 68 + k4 * 4];
        float4 wv3 = *(const float4*)&wlds[(t15 + 48) * 68 + k4 * 4];
        #pragma unroll
        for (int i = 0; i < 4; ++i) {
            float4 xv = *(const float4*)&xlds[(g * 4 + i) * 68 + k4 * 4];
            acc[i][0] += xv.x * wv0.x + xv.y * wv0.y + xv.z * wv0.z + xv.w * wv0.w;
            acc[i][1] += xv.x * wv1.x + xv.y * wv1.y + xv.z * wv1.z + xv.w * wv1.w;
            acc[i][2] += xv.x * wv2.x + xv.y * wv2.y + xv.z * wv2.z + xv.w * wv2.w;
            acc[i][3] += xv.x * wv3.x + xv.y * wv3.y + xv.z * wv3.z + xv.w * wv3.w;
        }
    }

    #pragma unroll
    for (int i = 0; i < 4; ++i) {
        int nl = g * 4 + i;
        int n = nb + nl;
        if (n < N_NODES) {
            float sc = slds[nl];
            h[n * D + t15     ] = (acc[i][0] + blds[t15     ]) * sc;
            h[n * D + t15 + 16] = (acc[i][1] + blds[t15 + 16]) * sc;
            h[n * D + t15 + 32] = (acc[i][2] + blds[t15 + 32]) * sc;
            h[n * D + t15 + 48] = (acc[i][3] + blds[t15 + 48]) * sc;
        }
    }
}

// ---------------------------------------------------------------------------
// K7: gather-accumulate per receiver + self-term + rsqrt + leaky-relu.
// ---------------------------------------------------------------------------
__global__ __launch_bounds__(256) void gather_kernel(
        const float* __restrict__ h, const int* __restrict__ rowoff,
        const ushort* __restrict__ csr16, float* __restrict__ out) {
    const int lane = threadIdx.x & 63;
    const int n = blockIdx.x * 4 + (threadIdx.x >> 6);
    if (n >= N_NODES) return;

    float acc = h[n * D + lane];           // self-edge contribution
    const int base = rowoff[n];
    const int cnt = rowoff[n + 1] - base;

    for (int j0 = 0; j0 < cnt; j0 += 64) {
        int m = cnt - j0; if (m > 64) m = 64;
        int my = (lane < m) ? (int)csr16[base + j0 + lane] : 0;
        int t = 0;
        for (; t + 8 <= m; t += 8) {
            float a0 = h[__shfl(my, t + 0) * D + lane];
            float a1 = h[__shfl(my, t + 1) * D + lane];
            float a2 = h[__shfl(my, t + 2) * D + lane];
            float a3 = h[__shfl(my, t + 3) * D + lane];
            float a4 = h[__shfl(my, t + 4) * D + lane];
            float a5 = h[__shfl(my, t + 5) * D + lane];
            float a6 = h[__shfl(my, t + 6) * D + lane];
            float a7 = h[__shfl(my, t + 7) * D + lane];
            acc += ((a0 + a1) + (a2 + a3)) + ((a4 + a5) + (a6 + a7));
        }
        for (; t < m; ++t) acc += h[__shfl(my, t) * D + lane];
    }
    float vv = acc * rsqrtf((float)(cnt + 1));
    out[n * D + lane] = vv > 0.0f ? vv : 0.01f * vv;
}

// ---------------------------------------------------------------------------
extern "C" void kernel_launch(void* const* d_in, const int* in_sizes, int n_in,
                              void* d_out, int out_size, void* d_ws, size_t ws_size,
                              hipStream_t stream) {
    const float* x       = (const float*)d_in[0];
    const int*   senders = (const int*)d_in[1];
    const int*   recvs   = (const int*)d_in[2];
    const float* weight  = (const float*)d_in[3];
    const float* bias    = (const float*)d_in[4];
    float* out = (float*)d_out;

    // workspace layout (256B-aligned chunks)
    char* p = (char*)d_ws;
    auto take = [&](size_t bytes) { char* q = p; p += (bytes + 255) & ~(size_t)255; return q; };
    float*         h      = (float*)take((size_t)N_NODES * D * 4);      // 12.8 MB
    float*         sscale = (float*)take((size_t)N_NODES * 4);          // 200 KB
    unsigned*      pr     = (unsigned*)take((size_t)N_EDGES * 4);       // 3.2 MB
    unsigned char* ps8    = (unsigned char*)take((size_t)N_EDGES);      // 0.8 MB
    int*           rcnt   = (int*)take((size_t)NB * NSLICE * 4);        // 150 KB
    int*           scnt   = (int*)take((size_t)NB * NSLICE * 4);        // 150 KB
    int*           rtot   = (int*)take((size_t)NB * 4);
    int*           stot   = (int*)take((size_t)NB * 4);
    int*           rbase  = (int*)take((size_t)(NB + 1) * 4);
    int*           sbase  = (int*)take((size_t)(NB + 1) * 4);
    int*           rowoff = (int*)take((size_t)(N_NODES + 1) * 4);      // 200 KB
    ushort*        csr16  = (ushort*)take((size_t)N_EDGES * 2);         // 1.6 MB

    hipLaunchKernelGGL(count_kernel, dim3(NSLICE), dim3(1024), 0, stream,
                       senders, recvs, rcnt, scnt);
    hipLaunchKernelGGL(scanA_kernel, dim3(2 * NB), dim3(256), 0, stream,
                       rcnt, scnt, rtot, stot);
    hipLaunchKernelGGL(scanB_kernel, dim3(1), dim3(256), 0, stream,
                       rtot, stot, rbase, sbase);
    hipLaunchKernelGGL(part_kernel, dim3(NSLICE), dim3(1024), 0, stream,
                       senders, recvs, rcnt, scnt, rbase, sbase, pr, ps8);
    hipLaunchKernelGGL(sscale_kernel, dim3(NB), dim3(BSZ), 0, stream,
                       sbase, ps8, sscale);
    hipLaunchKernelGGL(csr_kernel, dim3(NB), dim3(BSZ), 0, stream,
                       pr, rbase, rowoff, csr16);
    hipLaunchKernelGGL(linear_kernel, dim3((N_NODES + 63) / 64), dim3(256), 0, stream,
                       x, weight, bias, sscale, h);
    hipLaunchKernelGGL(gather_kernel, dim3((N_NODES + 3) / 4), dim3(256), 0, stream,
                       h, rowoff, csr16, out);
}

// Round 10
// 79.133 us; speedup vs baseline: 6.9595x; 1.1343x over previous
//
#include <hip/hip_runtime.h>

#define N_NODES 50000
#define N_EDGES 800000
#define D 64
#define NB 196            // buckets; 196*256 = 50176 >= 50000 (bucket = id >> 8)
#define BSZ 256           // nodes per bucket
#define NSLICE 196        // edge slices; 196*4096 = 802816 >= 800000
#define E4 (N_EDGES / 4)  // 200000 int4 groups

// bf16 helpers (round-to-nearest-even); fp32 accumulation everywhere.
__device__ __forceinline__ ushort f2bf(float f) {
    unsigned u = __float_as_uint(f);
    unsigned r = u + 0x7fffu + ((u >> 16) & 1u);
    return (ushort)(r >> 16);
}
__device__ __forceinline__ float bf2f(ushort s) {
    return __uint_as_float(((unsigned)s) << 16);
}

// ---------------------------------------------------------------------------
// K1: per-slice bucket histograms (receiver and sender). No global atomics.
// ---------------------------------------------------------------------------
__global__ __launch_bounds__(1024) void count_kernel(
        const int* __restrict__ s, const int* __restrict__ r,
        int* __restrict__ rcnt, int* __restrict__ scnt) {
    __shared__ int rh[NB], sh[NB];
    const int tid = threadIdx.x, sl = blockIdx.x;
    for (int i = tid; i < NB; i += 1024) { rh[i] = 0; sh[i] = 0; }
    __syncthreads();

    int e4 = sl * 1024 + tid;
    if (e4 < E4) {
        int4 rv = ((const int4*)r)[e4];
        int4 sv = ((const int4*)s)[e4];
        atomicAdd(&rh[rv.x >> 8], 1); atomicAdd(&rh[rv.y >> 8], 1);
        atomicAdd(&rh[rv.z >> 8], 1); atomicAdd(&rh[rv.w >> 8], 1);
        atomicAdd(&sh[sv.x >> 8], 1); atomicAdd(&sh[sv.y >> 8], 1);
        atomicAdd(&sh[sv.z >> 8], 1); atomicAdd(&sh[sv.w >> 8], 1);
    }
    __syncthreads();
    for (int i = tid; i < NB; i += 1024) {
        rcnt[i * NSLICE + sl] = rh[i];
        scnt[i * NSLICE + sl] = sh[i];
    }
}

// ---------------------------------------------------------------------------
// K2a: per-bucket scan of slice counts (392 blocks).
// ---------------------------------------------------------------------------
__global__ __launch_bounds__(256) void scanA_kernel(
        int* __restrict__ rcnt, int* __restrict__ scnt,
        int* __restrict__ rtot, int* __restrict__ stot) {
    __shared__ int sc[256];
    const int tid = threadIdx.x;
    const int b = blockIdx.x;
    int* arr = (b < NB) ? rcnt : scnt;
    int* tot = (b < NB) ? rtot : stot;
    const int bb = (b < NB) ? b : b - NB;

    int v = (tid < NSLICE) ? arr[bb * NSLICE + tid] : 0;
    sc[tid] = v;
    __syncthreads();
    for (int o = 1; o < 256; o <<= 1) {
        int u = (tid >= o) ? sc[tid - o] : 0;
        __syncthreads();
        sc[tid] += u;
        __syncthreads();
    }
    if (tid < NSLICE) arr[bb * NSLICE + tid] = sc[tid] - v;  // exclusive
    if (tid == 255) tot[bb] = sc[255];
}

// ---------------------------------------------------------------------------
// K2b: exclusive scan of the 196 bucket totals (both arrays). Tiny.
// ---------------------------------------------------------------------------
__global__ __launch_bounds__(256) void scanB_kernel(
        const int* __restrict__ rtot, const int* __restrict__ stot,
        int* __restrict__ rbase, int* __restrict__ sbase) {
    __shared__ int sc[256];
    const int tid = threadIdx.x;
    for (int pass = 0; pass < 2; ++pass) {
        const int* tot = pass ? stot : rtot;
        int* base = pass ? sbase : rbase;
        int v = (tid < NB) ? tot[tid] : 0;
        sc[tid] = v;
        __syncthreads();
        for (int o = 1; o < 256; o <<= 1) {
            int u = (tid >= o) ? sc[tid - o] : 0;
            __syncthreads();
            sc[tid] += u;
            __syncthreads();
        }
        if (tid < NB) base[tid] = sc[tid] - v;
        if (tid == 0) base[NB] = N_EDGES;
        __syncthreads();
    }
}

// ---------------------------------------------------------------------------
// K3: radix partition. LDS cursor atomics only.
// ---------------------------------------------------------------------------
__global__ __launch_bounds__(1024) void part_kernel(
        const int* __restrict__ s, const int* __restrict__ r,
        const int* __restrict__ rcnt, const int* __restrict__ scnt,
        const int* __restrict__ rbase, const int* __restrict__ sbase,
        unsigned* __restrict__ pr, unsigned char* __restrict__ ps8) {
    __shared__ int rcur[NB], scur[NB];
    const int tid = threadIdx.x, sl = blockIdx.x;
    for (int i = tid; i < NB; i += 1024) {
        rcur[i] = rbase[i] + rcnt[i * NSLICE + sl];
        scur[i] = sbase[i] + scnt[i * NSLICE + sl];
    }
    __syncthreads();

    int e4 = sl * 1024 + tid;
    if (e4 < E4) {
        int4 rv = ((const int4*)r)[e4];
        int4 sv = ((const int4*)s)[e4];
        int ri[4] = {rv.x, rv.y, rv.z, rv.w};
        int si[4] = {sv.x, sv.y, sv.z, sv.w};
        #pragma unroll
        for (int k = 0; k < 4; ++k) {
            int pos = atomicAdd(&rcur[ri[k] >> 8], 1);
            pr[pos] = ((unsigned)(ri[k] & 255) << 16) | (unsigned)si[k];
            int pos2 = atomicAdd(&scur[si[k] >> 8], 1);
            ps8[pos2] = (unsigned char)(si[k] & 255);
        }
    }
}

// ---------------------------------------------------------------------------
// K4 (merged): blocks [0,NB) do per-bucket CSR finalize; blocks [NB,2NB)
// do node-level sender degree -> sscale. Saves one launch.
// ---------------------------------------------------------------------------
__global__ __launch_bounds__(256) void post_kernel(
        const unsigned* __restrict__ pr, const int* __restrict__ rbase,
        int* __restrict__ rowoff, ushort* __restrict__ csr16,
        const int* __restrict__ sbase, const unsigned char* __restrict__ ps8,
        float* __restrict__ sscale) {
    const int tid = threadIdx.x;
    if (blockIdx.x >= NB) {
        // ---- sscale half ----
        __shared__ int hist[BSZ];
        const int b = blockIdx.x - NB;
        hist[tid] = 0;
        __syncthreads();
        const int sb = sbase[b], se = sbase[b + 1];
        for (int i = sb + tid; i < se; i += 256) atomicAdd(&hist[ps8[i]], 1);
        __syncthreads();
        int n = b * BSZ + tid;
        if (n < N_NODES) sscale[n] = rsqrtf((float)(hist[tid] + 1));  // +1 self
        return;
    }
    // ---- csr half ----
    __shared__ int hist2[BSZ];
    __shared__ int cur[BSZ];
    const int b = blockIdx.x;
    const int rb = rbase[b], re = rbase[b + 1];

    hist2[tid] = 0;
    __syncthreads();
    for (int i = rb + tid; i < re; i += 256)
        atomicAdd(&hist2[pr[i] >> 16], 1);
    __syncthreads();

    int v = hist2[tid];
    __syncthreads();
    hist2[tid] = v;
    __syncthreads();
    for (int o = 1; o < 256; o <<= 1) {
        int u = (tid >= o) ? hist2[tid - o] : 0;
        __syncthreads();
        hist2[tid] += u;
        __syncthreads();
    }
    int excl = hist2[tid] - v;
    int n = b * BSZ + tid;
    if (n < N_NODES) rowoff[n] = rb + excl;
    cur[tid] = rb + excl;
    if (b == NB - 1 && tid == 0) rowoff[N_NODES] = N_EDGES;
    __syncthreads();

    for (int i = rb + tid; i < re; i += 256) {
        unsigned pw = pr[i];
        int pos = atomicAdd(&cur[pw >> 16], 1);
        csr16[pos] = (ushort)(pw & 0xffffu);
    }
}

// ---------------------------------------------------------------------------
// K5: h16 = bf16((x @ W^T + b) * sscale[n]). LDS-tiled, pressure-capped
// (r8 lesson: full unroll hit the 256-VGPR clamp). bf16 h halves the
// gather's dominant read traffic; accumulation stays fp32.
// ---------------------------------------------------------------------------
__global__ __launch_bounds__(256, 4) void linear_kernel(
        const float* __restrict__ x, const float* __restrict__ w,
        const float* __restrict__ bias, const float* __restrict__ sscale,
        ushort* __restrict__ h16) {
    __shared__ float wlds[64 * 68];
    __shared__ float xlds[64 * 68];
    __shared__ float blds[64];
    __shared__ float slds[64];
    const int t = threadIdx.x;
    const int t15 = t & 15;
    const int g = t >> 4;           // 0..15: node group (4 nodes each)
    const int nb = blockIdx.x * 64;

    #pragma unroll
    for (int q = 0; q < 4; ++q) {   // stage W: 1024 float4
        int idx = q * 256 + t;
        int o = idx >> 4, k4 = idx & 15;
        float4 wv = ((const float4*)w)[idx];
        *(float4*)&wlds[o * 68 + k4 * 4] = wv;
    }
    if (t < 64) {
        blds[t] = bias[t];
        int n = nb + t;
        slds[t] = (n < N_NODES) ? sscale[n] : 0.f;
    }
    #pragma unroll
    for (int q = 0; q < 4; ++q) {   // stage x tile: 64 nodes x 16 float4
        int idx = q * 256 + t;
        int nl = idx >> 4, k4 = idx & 15;
        int n = nb + nl;
        float4 xv = (n < N_NODES) ? ((const float4*)x)[n * 16 + k4]
                                  : make_float4(0.f, 0.f, 0.f, 0.f);
        *(float4*)&xlds[nl * 68 + k4 * 4] = xv;
    }
    __syncthreads();

    float acc[4][4];
    #pragma unroll
    for (int i = 0; i < 4; ++i)
        #pragma unroll
        for (int j = 0; j < 4; ++j) acc[i][j] = 0.f;

    #pragma unroll 2
    for (int k4 = 0; k4 < 16; ++k4) {
        float4 wv0 = *(const float4*)&wlds[(t15     ) * 68 + k4 * 4];
        float4 wv1 = *(const float4*)&wlds[(t15 + 16) * 68 + k4 * 4];
        float4 wv2 = *(const float4*)&wlds[(t15 + 32) * 68 + k4 * 4];
        float4 wv3 = *(const float4*)&wlds[(t15 + 48) * 68 + k4 * 4];
        #pragma unroll
        for (int i = 0; i < 4; ++i) {
            float4 xv = *(const float4*)&xlds[(g * 4 + i) * 68 + k4 * 4];
            acc[i][0] += xv.x * wv0.x + xv.y * wv0.y + xv.z * wv0.z + xv.w * wv0.w;
            acc[i][1] += xv.x * wv1.x + xv.y * wv1.y + xv.z * wv1.z + xv.w * wv1.w;
            acc[i][2] += xv.x * wv2.x + xv.y * wv2.y + xv.z * wv2.z + xv.w * wv2.w;
            acc[i][3] += xv.x * wv3.x + xv.y * wv3.y + xv.z * wv3.z + xv.w * wv3.w;
        }
    }

    #pragma unroll
    for (int i = 0; i < 4; ++i) {
        int nl = g * 4 + i;
        int n = nb + nl;
        if (n < N_NODES) {
            float sc = slds[nl];
            h16[n * D + t15     ] = f2bf((acc[i][0] + blds[t15     ]) * sc);
            h16[n * D + t15 + 16] = f2bf((acc[i][1] + blds[t15 + 16]) * sc);
            h16[n * D + t15 + 32] = f2bf((acc[i][2] + blds[t15 + 32]) * sc);
            h16[n * D + t15 + 48] = f2bf((acc[i][3] + blds[t15 + 48]) * sc);
        }
    }
}

// ---------------------------------------------------------------------------
// K6: gather-accumulate per receiver + self-term + rsqrt + leaky-relu.
// bf16 h rows (128B/row), fp32 accumulation, 8-deep load batching.
// ---------------------------------------------------------------------------
__global__ __launch_bounds__(256) void gather_kernel(
        const ushort* __restrict__ h16, const int* __restrict__ rowoff,
        const ushort* __restrict__ csr16, float* __restrict__ out) {
    const int lane = threadIdx.x & 63;
    const int n = blockIdx.x * 4 + (threadIdx.x >> 6);
    if (n >= N_NODES) return;

    float acc = bf2f(h16[n * D + lane]);   // self-edge contribution
    const int base = rowoff[n];
    const int cnt = rowoff[n + 1] - base;

    for (int j0 = 0; j0 < cnt; j0 += 64) {
        int m = cnt - j0; if (m > 64) m = 64;
        int my = (lane < m) ? (int)csr16[base + j0 + lane] : 0;
        int t = 0;
        for (; t + 8 <= m; t += 8) {
            ushort a0 = h16[__shfl(my, t + 0) * D + lane];
            ushort a1 = h16[__shfl(my, t + 1) * D + lane];
            ushort a2 = h16[__shfl(my, t + 2) * D + lane];
            ushort a3 = h16[__shfl(my, t + 3) * D + lane];
            ushort a4 = h16[__shfl(my, t + 4) * D + lane];
            ushort a5 = h16[__shfl(my, t + 5) * D + lane];
            ushort a6 = h16[__shfl(my, t + 6) * D + lane];
            ushort a7 = h16[__shfl(my, t + 7) * D + lane];
            acc += ((bf2f(a0) + bf2f(a1)) + (bf2f(a2) + bf2f(a3)))
                 + ((bf2f(a4) + bf2f(a5)) + (bf2f(a6) + bf2f(a7)));
        }
        for (; t < m; ++t) acc += bf2f(h16[__shfl(my, t) * D + lane]);
    }
    float vv = acc * rsqrtf((float)(cnt + 1));
    out[n * D + lane] = vv > 0.0f ? vv : 0.01f * vv;
}

// ---------------------------------------------------------------------------
extern "C" void kernel_launch(void* const* d_in, const int* in_sizes, int n_in,
                              void* d_out, int out_size, void* d_ws, size_t ws_size,
                              hipStream_t stream) {
    const float* x       = (const float*)d_in[0];
    const int*   senders = (const int*)d_in[1];
    const int*   recvs   = (const int*)d_in[2];
    const float* weight  = (const float*)d_in[3];
    const float* bias    = (const float*)d_in[4];
    float* out = (float*)d_out;

    // workspace layout (256B-aligned chunks)
    char* p = (char*)d_ws;
    auto take = [&](size_t bytes) { char* q = p; p += (bytes + 255) & ~(size_t)255; return q; };
    ushort*        h16    = (ushort*)take((size_t)N_NODES * D * 2);     // 6.4 MB
    float*         sscale = (float*)take((size_t)N_NODES * 4);          // 200 KB
    unsigned*      pr     = (unsigned*)take((size_t)N_EDGES * 4);       // 3.2 MB
    unsigned char* ps8    = (unsigned char*)take((size_t)N_EDGES);      // 0.8 MB
    int*           rcnt   = (int*)take((size_t)NB * NSLICE * 4);        // 150 KB
    int*           scnt   = (int*)take((size_t)NB * NSLICE * 4);        // 150 KB
    int*           rtot   = (int*)take((size_t)NB * 4);
    int*           stot   = (int*)take((size_t)NB * 4);
    int*           rbase  = (int*)take((size_t)(NB + 1) * 4);
    int*           sbase  = (int*)take((size_t)(NB + 1) * 4);
    int*           rowoff = (int*)take((size_t)(N_NODES + 1) * 4);      // 200 KB
    ushort*        csr16  = (ushort*)take((size_t)N_EDGES * 2);         // 1.6 MB

    hipLaunchKernelGGL(count_kernel, dim3(NSLICE), dim3(1024), 0, stream,
                       senders, recvs, rcnt, scnt);
    hipLaunchKernelGGL(scanA_kernel, dim3(2 * NB), dim3(256), 0, stream,
                       rcnt, scnt, rtot, stot);
    hipLaunchKernelGGL(scanB_kernel, dim3(1), dim3(256), 0, stream,
                       rtot, stot, rbase, sbase);
    hipLaunchKernelGGL(part_kernel, dim3(NSLICE), dim3(1024), 0, stream,
                       senders, recvs, rcnt, scnt, rbase, sbase, pr, ps8);
    hipLaunchKernelGGL(post_kernel, dim3(2 * NB), dim3(BSZ), 0, stream,
                       pr, rbase, rowoff, csr16, sbase, ps8, sscale);
    hipLaunchKernelGGL(linear_kernel, dim3((N_NODES + 63) / 64), dim3(256), 0, stream,
                       x, weight, bias, sscale, h16);
    hipLaunchKernelGGL(gather_kernel, dim3((N_NODES + 3) / 4), dim3(256), 0, stream,
                       h16, rowoff, csr16, out);
}

// Round 12
// 76.916 us; speedup vs baseline: 7.1601x; 1.0288x over previous
//
#include <hip/hip_runtime.h>

#define N_NODES 50000
#define N_EDGES 800000
#define D 64
#define NB 196            // buckets; 196*256 = 50176 >= 50000 (bucket = id >> 8)
#define BSZ 256           // nodes per bucket
#define NSLICE 196        // edge slices; 196*4096 = 802816 >= 800000
#define E4 (N_EDGES / 4)  // 200000 int4 groups

// bf16 helpers (round-to-nearest-even); fp32 accumulation everywhere.
__device__ __forceinline__ ushort f2bf(float f) {
    unsigned u = __float_as_uint(f);
    unsigned r = u + 0x7fffu + ((u >> 16) & 1u);
    return (ushort)(r >> 16);
}
__device__ __forceinline__ void acc8(const uint4 a, float* acc) {
    acc[0] += __uint_as_float(a.x << 16);
    acc[1] += __uint_as_float(a.x & 0xffff0000u);
    acc[2] += __uint_as_float(a.y << 16);
    acc[3] += __uint_as_float(a.y & 0xffff0000u);
    acc[4] += __uint_as_float(a.z << 16);
    acc[5] += __uint_as_float(a.z & 0xffff0000u);
    acc[6] += __uint_as_float(a.w << 16);
    acc[7] += __uint_as_float(a.w & 0xffff0000u);
}

// ---------------------------------------------------------------------------
// K1: per-slice bucket histograms (receiver and sender). No global atomics.
// ---------------------------------------------------------------------------
__global__ __launch_bounds__(1024) void count_kernel(
        const int* __restrict__ s, const int* __restrict__ r,
        int* __restrict__ rcnt, int* __restrict__ scnt) {
    __shared__ int rh[NB], sh[NB];
    const int tid = threadIdx.x, sl = blockIdx.x;
    for (int i = tid; i < NB; i += 1024) { rh[i] = 0; sh[i] = 0; }
    __syncthreads();

    int e4 = sl * 1024 + tid;
    if (e4 < E4) {
        int4 rv = ((const int4*)r)[e4];
        int4 sv = ((const int4*)s)[e4];
        atomicAdd(&rh[rv.x >> 8], 1); atomicAdd(&rh[rv.y >> 8], 1);
        atomicAdd(&rh[rv.z >> 8], 1); atomicAdd(&rh[rv.w >> 8], 1);
        atomicAdd(&sh[sv.x >> 8], 1); atomicAdd(&sh[sv.y >> 8], 1);
        atomicAdd(&sh[sv.z >> 8], 1); atomicAdd(&sh[sv.w >> 8], 1);
    }
    __syncthreads();
    for (int i = tid; i < NB; i += 1024) {
        rcnt[i * NSLICE + sl] = rh[i];
        scnt[i * NSLICE + sl] = sh[i];
    }
}

// ---------------------------------------------------------------------------
// K2: per-bucket scan of slice counts (392 blocks). Writes bucket totals.
// ---------------------------------------------------------------------------
__global__ __launch_bounds__(256) void scanA_kernel(
        int* __restrict__ rcnt, int* __restrict__ scnt,
        int* __restrict__ rtot, int* __restrict__ stot) {
    __shared__ int sc[256];
    const int tid = threadIdx.x;
    const int b = blockIdx.x;
    int* arr = (b < NB) ? rcnt : scnt;
    int* tot = (b < NB) ? rtot : stot;
    const int bb = (b < NB) ? b : b - NB;

    int v = (tid < NSLICE) ? arr[bb * NSLICE + tid] : 0;
    sc[tid] = v;
    __syncthreads();
    for (int o = 1; o < 256; o <<= 1) {
        int u = (tid >= o) ? sc[tid - o] : 0;
        __syncthreads();
        sc[tid] += u;
        __syncthreads();
    }
    if (tid < NSLICE) arr[bb * NSLICE + tid] = sc[tid] - v;  // exclusive
    if (tid == 255) tot[bb] = sc[255];
}

// ---------------------------------------------------------------------------
// K3: radix partition. Bucket bases recomputed locally from rtot/stot.
// LDS cursor atomics only.
// ---------------------------------------------------------------------------
__global__ __launch_bounds__(1024) void part_kernel(
        const int* __restrict__ s, const int* __restrict__ r,
        const int* __restrict__ rcnt, const int* __restrict__ scnt,
        const int* __restrict__ rtot, const int* __restrict__ stot,
        unsigned* __restrict__ pr, unsigned char* __restrict__ ps8) {
    __shared__ int rcur[NB], scur[NB];
    __shared__ int sc[256];
    const int tid = threadIdx.x, sl = blockIdx.x;

    // local inclusive scan of rtot -> per-bucket global base
    if (tid < 256) sc[tid] = (tid < NB) ? rtot[tid] : 0;
    __syncthreads();
    for (int o = 1; o < 256; o <<= 1) {
        int u = 0;
        if (tid < 256 && tid >= o) u = sc[tid - o];
        __syncthreads();
        if (tid < 256) sc[tid] += u;
        __syncthreads();
    }
    if (tid < NB) rcur[tid] = ((tid == 0) ? 0 : sc[tid - 1]) + rcnt[tid * NSLICE + sl];
    __syncthreads();
    if (tid < 256) sc[tid] = (tid < NB) ? stot[tid] : 0;
    __syncthreads();
    for (int o = 1; o < 256; o <<= 1) {
        int u = 0;
        if (tid < 256 && tid >= o) u = sc[tid - o];
        __syncthreads();
        if (tid < 256) sc[tid] += u;
        __syncthreads();
    }
    if (tid < NB) scur[tid] = ((tid == 0) ? 0 : sc[tid - 1]) + scnt[tid * NSLICE + sl];
    __syncthreads();

    int e4 = sl * 1024 + tid;
    if (e4 < E4) {
        int4 rv = ((const int4*)r)[e4];
        int4 sv = ((const int4*)s)[e4];
        int ri[4] = {rv.x, rv.y, rv.z, rv.w};
        int si[4] = {sv.x, sv.y, sv.z, sv.w};
        #pragma unroll
        for (int k = 0; k < 4; ++k) {
            int pos = atomicAdd(&rcur[ri[k] >> 8], 1);
            pr[pos] = ((unsigned)(ri[k] & 255) << 16) | (unsigned)si[k];
            int pos2 = atomicAdd(&scur[si[k] >> 8], 1);
            ps8[pos2] = (unsigned char)(si[k] & 255);
        }
    }
}

// ---------------------------------------------------------------------------
// K4 (merged): blocks [0,NB) build per-bucket CSR; blocks [NB,2NB) compute
// sender-degree sscale. Bucket bases recomputed locally.
// ---------------------------------------------------------------------------
__global__ __launch_bounds__(256) void post_kernel(
        const unsigned* __restrict__ pr,
        const int* __restrict__ rtot, const int* __restrict__ stot,
        int* __restrict__ rowoff, ushort* __restrict__ csr16,
        const unsigned char* __restrict__ ps8, float* __restrict__ sscale) {
    __shared__ int sc[256];
    const int tid = threadIdx.x;

    if (blockIdx.x >= NB) {
        // ---- sscale half ----
        __shared__ int hist[BSZ];
        const int b = blockIdx.x - NB;
        sc[tid] = (tid < NB) ? stot[tid] : 0;
        __syncthreads();
        for (int o = 1; o < 256; o <<= 1) {
            int u = (tid >= o) ? sc[tid - o] : 0;
            __syncthreads();
            sc[tid] += u;
            __syncthreads();
        }
        const int sb = (b == 0) ? 0 : sc[b - 1];
        const int se = sc[b];
        hist[tid] = 0;
        __syncthreads();
        for (int i = sb + tid; i < se; i += 256) atomicAdd(&hist[ps8[i]], 1);
        __syncthreads();
        int n = b * BSZ + tid;
        if (n < N_NODES) sscale[n] = rsqrtf((float)(hist[tid] + 1));  // +1 self
        return;
    }
    // ---- csr half ----
    __shared__ int hist2[BSZ];
    __shared__ int cur[BSZ];
    const int b = blockIdx.x;
    sc[tid] = (tid < NB) ? rtot[tid] : 0;
    __syncthreads();
    for (int o = 1; o < 256; o <<= 1) {
        int u = (tid >= o) ? sc[tid - o] : 0;
        __syncthreads();
        sc[tid] += u;
        __syncthreads();
    }
    const int rb = (b == 0) ? 0 : sc[b - 1];
    const int re = sc[b];

    hist2[tid] = 0;
    __syncthreads();
    for (int i = rb + tid; i < re; i += 256)
        atomicAdd(&hist2[pr[i] >> 16], 1);
    __syncthreads();

    int v = hist2[tid];
    __syncthreads();
    hist2[tid] = v;
    __syncthreads();
    for (int o = 1; o < 256; o <<= 1) {
        int u = (tid >= o) ? hist2[tid - o] : 0;
        __syncthreads();
        hist2[tid] += u;
        __syncthreads();
    }
    int excl = hist2[tid] - v;
    int n = b * BSZ + tid;
    if (n < N_NODES) rowoff[n] = rb + excl;
    cur[tid] = rb + excl;
    if (b == NB - 1 && tid == 0) rowoff[N_NODES] = N_EDGES;
    __syncthreads();

    for (int i = rb + tid; i < re; i += 256) {
        unsigned pw = pr[i];
        int pos = atomicAdd(&cur[pw >> 16], 1);
        csr16[pos] = (ushort)(pw & 0xffffu);
    }
}

// ---------------------------------------------------------------------------
// K5: h16 = bf16((x @ W^T + b) * sscale[n]). LDS-tiled, pressure-capped
// (r8 lesson: full unroll hit the 256-VGPR clamp -> 1 wave/SIMD).
// ---------------------------------------------------------------------------
__global__ __launch_bounds__(256, 4) void linear_kernel(
        const float* __restrict__ x, const float* __restrict__ w,
        const float* __restrict__ bias, const float* __restrict__ sscale,
        ushort* __restrict__ h16) {
    __shared__ float wlds[64 * 68];
    __shared__ float xlds[64 * 68];
    __shared__ float blds[64];
    __shared__ float slds[64];
    const int t = threadIdx.x;
    const int t15 = t & 15;
    const int g = t >> 4;           // 0..15: node group (4 nodes each)
    const int nb = blockIdx.x * 64;

    #pragma unroll
    for (int q = 0; q < 4; ++q) {   // stage W: 1024 float4
        int idx = q * 256 + t;
        int o = idx >> 4, k4 = idx & 15;
        float4 wv = ((const float4*)w)[idx];
        *(float4*)&wlds[o * 68 + k4 * 4] = wv;
    }
    if (t < 64) {
        blds[t] = bias[t];
        int n = nb + t;
        slds[t] = (n < N_NODES) ? sscale[n] : 0.f;
    }
    #pragma unroll
    for (int q = 0; q < 4; ++q) {   // stage x tile: 64 nodes x 16 float4
        int idx = q * 256 + t;
        int nl = idx >> 4, k4 = idx & 15;
        int n = nb + nl;
        float4 xv = (n < N_NODES) ? ((const float4*)x)[n * 16 + k4]
                                  : make_float4(0.f, 0.f, 0.f, 0.f);
        *(float4*)&xlds[nl * 68 + k4 * 4] = xv;
    }
    __syncthreads();

    float acc[4][4];
    #pragma unroll
    for (int i = 0; i < 4; ++i)
        #pragma unroll
        for (int j = 0; j < 4; ++j) acc[i][j] = 0.f;

    #pragma unroll 2
    for (int k4 = 0; k4 < 16; ++k4) {
        float4 wv0 = *(const float4*)&wlds[(t15     ) * 68 + k4 * 4];
        float4 wv1 = *(const float4*)&wlds[(t15 + 16) * 68 + k4 * 4];
        float4 wv2 = *(const float4*)&wlds[(t15 + 32) * 68 + k4 * 4];
        float4 wv3 = *(const float4*)&wlds[(t15 + 48) * 68 + k4 * 4];
        #pragma unroll
        for (int i = 0; i < 4; ++i) {
            float4 xv = *(const float4*)&xlds[(g * 4 + i) * 68 + k4 * 4];
            acc[i][0] += xv.x * wv0.x + xv.y * wv0.y + xv.z * wv0.z + xv.w * wv0.w;
            acc[i][1] += xv.x * wv1.x + xv.y * wv1.y + xv.z * wv1.z + xv.w * wv1.w;
            acc[i][2] += xv.x * wv2.x + xv.y * wv2.y + xv.z * wv2.z + xv.w * wv2.w;
            acc[i][3] += xv.x * wv3.x + xv.y * wv3.y + xv.z * wv3.z + xv.w * wv3.w;
        }
    }

    #pragma unroll
    for (int i = 0; i < 4; ++i) {
        int nl = g * 4 + i;
        int n = nb + nl;
        if (n < N_NODES) {
            float sc = slds[nl];
            h16[n * D + t15     ] = f2bf((acc[i][0] + blds[t15     ]) * sc);
            h16[n * D + t15 + 16] = f2bf((acc[i][1] + blds[t15 + 16]) * sc);
            h16[n * D + t15 + 32] = f2bf((acc[i][2] + blds[t15 + 32]) * sc);
            h16[n * D + t15 + 48] = f2bf((acc[i][3] + blds[t15 + 48]) * sc);
        }
    }
}

// ---------------------------------------------------------------------------
// K6: gather-accumulate, wide-load layout. Wave per node; 8-lane group per
// row, uint4 (8 bf16) per lane -> one wave load fetches 8 rows (1KB).
// ALL __shfl calls execute with the full wave active (divergence only around
// the loads) — r11 post-mortem: divergent __shfl w/ inactive source lane is
// undefined on CDNA and corrupted the ragged tail.
// ---------------------------------------------------------------------------
__global__ __launch_bounds__(256) void gather_kernel(
        const ushort* __restrict__ h16, const int* __restrict__ rowoff,
        const ushort* __restrict__ csr16, float* __restrict__ out) {
    const int lane = threadIdx.x & 63;
    const int q = lane & 7;        // channel octet: channels q*8 .. q*8+7
    const int g = lane >> 3;       // edge sub-slot 0..7
    const int n = blockIdx.x * 4 + (threadIdx.x >> 6);
    if (n >= N_NODES) return;

    float acc[8];
    #pragma unroll
    for (int k = 0; k < 8; ++k) acc[k] = 0.f;

    const int base = rowoff[n];
    const int cnt = rowoff[n + 1] - base;

    for (int j0 = 0; j0 < cnt; j0 += 64) {
        int m = cnt - j0; if (m > 64) m = 64;
        int my = (lane < m) ? (int)csr16[base + j0 + lane] : 0;
        int t = 0;
        for (; t + 16 <= m; t += 16) {          // two full 8-edge slots
            int s0 = __shfl(my, t + g);         // uniform loop: all lanes active
            int s1 = __shfl(my, t + 8 + g);
            uint4 a = *(const uint4*)&h16[s0 * D + q * 8];
            uint4 b = *(const uint4*)&h16[s1 * D + q * 8];
            acc8(a, acc);
            acc8(b, acc);
        }
        for (; t < m; t += 8) {                 // ragged tail slots
            int e = t + g;
            int ee = (e < m) ? e : 0;           // in-range source lane
            int s0 = __shfl(my, ee);            // executed by ALL lanes
            if (e < m) {                        // divergence only around load
                uint4 a = *(const uint4*)&h16[s0 * D + q * 8];
                acc8(a, acc);
            }
        }
    }

    // reduce the 8 edge-groups (all lanes active)
    #pragma unroll
    for (int k = 0; k < 8; ++k) acc[k] += __shfl_xor(acc[k], 8);
    #pragma unroll
    for (int k = 0; k < 8; ++k) acc[k] += __shfl_xor(acc[k], 16);
    #pragma unroll
    for (int k = 0; k < 8; ++k) acc[k] += __shfl_xor(acc[k], 32);

    // self term (added once per lane, post-reduction) + normalize + leaky
    uint4 sv = *(const uint4*)&h16[n * D + q * 8];
    acc8(sv, acc);
    float sc = rsqrtf((float)(cnt + 1));
    float o[8];
    #pragma unroll
    for (int k = 0; k < 8; ++k) {
        float vv = acc[k] * sc;
        o[k] = vv > 0.f ? vv : 0.01f * vv;
    }
    if (g == 0) {
        float4* op = (float4*)(out + n * D + q * 8);
        op[0] = make_float4(o[0], o[1], o[2], o[3]);
        op[1] = make_float4(o[4], o[5], o[6], o[7]);
    }
}

// ---------------------------------------------------------------------------
extern "C" void kernel_launch(void* const* d_in, const int* in_sizes, int n_in,
                              void* d_out, int out_size, void* d_ws, size_t ws_size,
                              hipStream_t stream) {
    const float* x       = (const float*)d_in[0];
    const int*   senders = (const int*)d_in[1];
    const int*   recvs   = (const int*)d_in[2];
    const float* weight  = (const float*)d_in[3];
    const float* bias    = (const float*)d_in[4];
    float* out = (float*)d_out;

    // workspace layout (256B-aligned chunks)
    char* p = (char*)d_ws;
    auto take = [&](size_t bytes) { char* q = p; p += (bytes + 255) & ~(size_t)255; return q; };
    ushort*        h16    = (ushort*)take((size_t)N_NODES * D * 2);     // 6.4 MB
    float*         sscale = (float*)take((size_t)N_NODES * 4);          // 200 KB
    unsigned*      pr     = (unsigned*)take((size_t)N_EDGES * 4);       // 3.2 MB
    unsigned char* ps8    = (unsigned char*)take((size_t)N_EDGES);      // 0.8 MB
    int*           rcnt   = (int*)take((size_t)NB * NSLICE * 4);        // 150 KB
    int*           scnt   = (int*)take((size_t)NB * NSLICE * 4);        // 150 KB
    int*           rtot   = (int*)take((size_t)NB * 4);
    int*           stot   = (int*)take((size_t)NB * 4);
    int*           rowoff = (int*)take((size_t)(N_NODES + 1) * 4);      // 200 KB
    ushort*        csr16  = (ushort*)take((size_t)N_EDGES * 2);         // 1.6 MB

    hipLaunchKernelGGL(count_kernel, dim3(NSLICE), dim3(1024), 0, stream,
                       senders, recvs, rcnt, scnt);
    hipLaunchKernelGGL(scanA_kernel, dim3(2 * NB), dim3(256), 0, stream,
                       rcnt, scnt, rtot, stot);
    hipLaunchKernelGGL(part_kernel, dim3(NSLICE), dim3(1024), 0, stream,
                       senders, recvs, rcnt, scnt, rtot, stot, pr, ps8);
    hipLaunchKernelGGL(post_kernel, dim3(2 * NB), dim3(BSZ), 0, stream,
                       pr, rtot, stot, rowoff, csr16, ps8, sscale);
    hipLaunchKernelGGL(linear_kernel, dim3((N_NODES + 63) / 64), dim3(256), 0, stream,
                       x, weight, bias, sscale, h16);
    hipLaunchKernelGGL(gather_kernel, dim3((N_NODES + 3) / 4), dim3(256), 0, stream,
                       h16, rowoff, csr16, out);
}